// Round 1
// baseline (523.402 us; speedup 1.0000x reference)
//
#include <hip/hip_runtime.h>
#include <math.h>

typedef unsigned int u32;
typedef unsigned short u16;
typedef __attribute__((ext_vector_type(8))) short short8;
typedef __attribute__((ext_vector_type(4))) float f32x4;

__device__ __forceinline__ u16 f2bf(float f) {
  u32 u = __builtin_bit_cast(u32, f);
  u += 0x7FFFu + ((u >> 16) & 1u);
  return (u16)(u >> 16);
}
__device__ __forceinline__ float bf2f(u16 h) {
  u32 u = ((u32)h) << 16;
  return __builtin_bit_cast(float, u);
}
__device__ __forceinline__ void gload_lds16(const void* g, void* l) {
  __builtin_amdgcn_global_load_lds((const __attribute__((address_space(1))) u32*)g,
                                   (__attribute__((address_space(3))) u32*)l, 16, 0, 0);
}
__device__ __forceinline__ f32x4 mfma16(short8 a, short8 b, f32x4 c) {
  return __builtin_amdgcn_mfma_f32_16x16x32_bf16(a, b, c, 0, 0, 0);
}

// ---------------- transpose+cast: src fp32 [K][N] -> dst bf16 [N][K] ----------------
__global__ __launch_bounds__(256) void transpose_cast(const float* __restrict__ src,
                                                      u16* __restrict__ dst, int K, int N) {
  __shared__ __attribute__((aligned(16))) u16 tile[64][72];
  const int n0 = blockIdx.x * 64, k0 = blockIdx.y * 64;
  const int t = threadIdx.x;
  const int tr = t >> 4;          // 0..15
  const int tc4 = (t & 15) * 4;   // 0..60
#pragma unroll
  for (int p = 0; p < 4; ++p) {
    int row = p * 16 + tr;  // k-local
    const float4 v = *(const float4*)(src + (size_t)(k0 + row) * N + n0 + tc4);
    tile[tc4 + 0][row] = f2bf(v.x);
    tile[tc4 + 1][row] = f2bf(v.y);
    tile[tc4 + 2][row] = f2bf(v.z);
    tile[tc4 + 3][row] = f2bf(v.w);
  }
  __syncthreads();
  const int nr = t >> 2;          // 0..63
  const int kc = (t & 3) * 16;    // 0,16,32,48
  u16* d = dst + (size_t)(n0 + nr) * K + k0 + kc;
  *(short8*)(d) = *(const short8*)&tile[nr][kc];
  *(short8*)(d + 8) = *(const short8*)&tile[nr][kc + 8];
}

// ---------------- transpose V out of qkv: -> vT[h][d][kv] ----------------
__global__ __launch_bounds__(256) void transpose_v(const u16* __restrict__ qkv,
                                                   u16* __restrict__ vT) {
  __shared__ __attribute__((aligned(16))) u16 tile[64][72];
  const int kv0 = blockIdx.x * 64, d0 = blockIdx.y * 64, h = blockIdx.z;
  const int t = threadIdx.x;
  const int tr = t >> 3;         // 0..31
  const int tc8 = (t & 7) * 8;
#pragma unroll
  for (int p = 0; p < 2; ++p) {
    int row = p * 32 + tr;  // kv-local
    short8 v = *(const short8*)(qkv + (size_t)(kv0 + row) * 6144 + 4096 + h * 128 + d0 + tc8);
#pragma unroll
    for (int j = 0; j < 8; ++j) tile[tc8 + j][row] = (u16)v[j];
  }
  __syncthreads();
  const int dr = t >> 2;          // 0..63
  const int kc = (t & 3) * 16;
  u16* dst = vT + ((size_t)h * 128 + d0 + dr) * 2048 + kv0 + kc;
  *(short8*)dst = *(const short8*)&tile[dr][kc];
  *(short8*)(dst + 8) = *(const short8*)&tile[dr][kc + 8];
}

// ---------------- LayerNorm: fp32 [2048 rows][2048] -> bf16 ----------------
__global__ __launch_bounds__(256) void ln_kernel(const float* __restrict__ x,
                                                 const float* __restrict__ gw,
                                                 const float* __restrict__ bw,
                                                 u16* __restrict__ out) {
  const int row = blockIdx.x, t = threadIdx.x;
  const float* xr = x + (size_t)row * 2048;
  const float4 v0 = *(const float4*)(xr + t * 8);
  const float4 v1 = *(const float4*)(xr + t * 8 + 4);
  float s = v0.x + v0.y + v0.z + v0.w + v1.x + v1.y + v1.z + v1.w;
  float q = v0.x * v0.x + v0.y * v0.y + v0.z * v0.z + v0.w * v0.w +
            v1.x * v1.x + v1.y * v1.y + v1.z * v1.z + v1.w * v1.w;
#pragma unroll
  for (int w = 32; w; w >>= 1) { s += __shfl_xor(s, w); q += __shfl_xor(q, w); }
  __shared__ float rs[4], rq[4];
  const int wid = t >> 6, lane = t & 63;
  if (!lane) { rs[wid] = s; rq[wid] = q; }
  __syncthreads();
  s = rs[0] + rs[1] + rs[2] + rs[3];
  q = rq[0] + rq[1] + rq[2] + rq[3];
  const float mu = s * (1.f / 2048.f);
  const float var = q * (1.f / 2048.f) - mu * mu;
  const float rstd = rsqrtf(var + 1e-5f);
  const float4 g0 = *(const float4*)(gw + t * 8);
  const float4 g1 = *(const float4*)(gw + t * 8 + 4);
  const float4 b0 = *(const float4*)(bw + t * 8);
  const float4 b1 = *(const float4*)(bw + t * 8 + 4);
  short8 o;
  o[0] = (short)f2bf((v0.x - mu) * rstd * g0.x + b0.x);
  o[1] = (short)f2bf((v0.y - mu) * rstd * g0.y + b0.y);
  o[2] = (short)f2bf((v0.z - mu) * rstd * g0.z + b0.z);
  o[3] = (short)f2bf((v0.w - mu) * rstd * g0.w + b0.w);
  o[4] = (short)f2bf((v1.x - mu) * rstd * g1.x + b1.x);
  o[5] = (short)f2bf((v1.y - mu) * rstd * g1.y + b1.y);
  o[6] = (short)f2bf((v1.z - mu) * rstd * g1.z + b1.z);
  o[7] = (short)f2bf((v1.w - mu) * rstd * g1.w + b1.w);
  *(short8*)(out + (size_t)row * 2048 + t * 8) = o;
}

// ---------------- GEMM: C[M][N] = A[M][K](bf16) @ Bt[N][K]^T (bf16), epilogues ----------------
// EPI 0: out bf16 plain           (QKV proj)
// EPI 1: out f32 = v+bias+res1    (attn out proj + x residual)
// EPI 2: out bf16 = gelu(v+bias)  (FF1)
// EPI 3: out f32 = v+bias+res1+bf(res2)  (FF2 + x1 + g)
template <int EPI>
__global__ __launch_bounds__(256) void gemm_kernel(const u16* __restrict__ A,
                                                   const u16* __restrict__ Bt,
                                                   int M, int N, int K,
                                                   float* __restrict__ outF,
                                                   u16* __restrict__ outB,
                                                   const float* __restrict__ bias,
                                                   const float* __restrict__ res1,
                                                   const u16* __restrict__ res2) {
  __shared__ __attribute__((aligned(16))) u16 lsA[128 * 64];
  __shared__ __attribute__((aligned(16))) u16 lsB[128 * 64];
  const int m0 = blockIdx.y * 128, n0 = blockIdx.x * 128;
  const int tid = threadIdx.x, wid = tid >> 6, lane = tid & 63;
  const int wm = (wid >> 1) * 64, wn = (wid & 1) * 64;
  const int lq = lane & 15, lk = lane >> 4;
  const int rIn = lane >> 3, sIn = lane & 7;  // stage: 8 lanes/row of 64 elems
  f32x4 acc[4][4] = {};

  for (int kt = 0; kt < K; kt += 64) {
    if (kt) __syncthreads();
#pragma unroll
    for (int i = 0; i < 4; ++i) {
      int c = wid * 4 + i;
      int row = c * 8 + rIn;
      int scol = (sIn ^ (row & 7)) * 8;
      gload_lds16(A + (size_t)(m0 + row) * K + kt + scol, lsA + c * 512);
      gload_lds16(Bt + (size_t)(n0 + row) * K + kt + scol, lsB + c * 512);
    }
    __syncthreads();
#pragma unroll
    for (int kk = 0; kk < 2; ++kk) {
      short8 af[4], bfr[4];
#pragma unroll
      for (int i = 0; i < 4; ++i) {
        int ra = wm + i * 16 + lq;
        af[i] = *(const short8*)((const char*)lsA + ra * 128 +
                                 ((kk * 64 + lk * 16) ^ ((ra & 7) << 4)));
        int rb = wn + i * 16 + lq;
        bfr[i] = *(const short8*)((const char*)lsB + rb * 128 +
                                  ((kk * 64 + lk * 16) ^ ((rb & 7) << 4)));
      }
#pragma unroll
      for (int mi = 0; mi < 4; ++mi)
#pragma unroll
        for (int ni = 0; ni < 4; ++ni)
          acc[mi][ni] = mfma16(af[mi], bfr[ni], acc[mi][ni]);
    }
  }
#pragma unroll
  for (int mi = 0; mi < 4; ++mi) {
#pragma unroll
    for (int ni = 0; ni < 4; ++ni) {
      const int col = n0 + wn + ni * 16 + lq;
#pragma unroll
      for (int r = 0; r < 4; ++r) {
        const int row = m0 + wm + mi * 16 + lk * 4 + r;
        const size_t idx = (size_t)row * N + col;
        float v = acc[mi][ni][r];
        if (EPI == 0) {
          outB[idx] = f2bf(v);
        } else if (EPI == 1) {
          outF[idx] = v + bias[col] + res1[idx];
        } else if (EPI == 2) {
          float xg = v + bias[col];
          outB[idx] = f2bf(0.5f * xg * (1.f + erff(xg * 0.70710678118654752f)));
        } else {
          outF[idx] = v + bias[col] + res1[idx] + bf2f(res2[idx]);
        }
      }
    }
  }
}

// ---------------- flash attention (causal), 4 waves x 16 q-rows, KVBLK=64 ----------------
__global__ __launch_bounds__(256) void attn_kernel(const u16* __restrict__ qkv,
                                                   const u16* __restrict__ vT,
                                                   u16* __restrict__ attnout) {
  __shared__ __attribute__((aligned(16))) u16 lsK[64 * 128];   // [kv][d], swizzled
  __shared__ __attribute__((aligned(16))) u16 lsV[128 * 64];   // [d][kv], swizzled
  __shared__ __attribute__((aligned(16))) u16 lsP[4][16 * 64]; // per-wave P, swizzled
  const int h = blockIdx.y;
  const int qb = blockIdx.x * 64;
  const int tid = threadIdx.x, wid = tid >> 6, lane = tid & 63;
  const int lq = lane & 15, lk = lane >> 4;
  const int qw = qb + wid * 16;

  short8 qf[4];
  {
    const u16* qp = qkv + (size_t)(qw + lq) * 6144 + h * 128;
#pragma unroll
    for (int ks = 0; ks < 4; ++ks) qf[ks] = *(const short8*)(qp + ks * 32 + lk * 8);
  }
  float mreg[4], lreg[4];
  f32x4 o[8];
#pragma unroll
  for (int r = 0; r < 4; ++r) { mreg[r] = -INFINITY; lreg[r] = 0.f; }
#pragma unroll
  for (int dt = 0; dt < 8; ++dt) o[dt] = (f32x4){0.f, 0.f, 0.f, 0.f};

  const int rK = lane >> 4, sK = lane & 15;  // K-tile: rows of 128 elems, 16 lanes/row
  const int rV = lane >> 3, sV = lane & 7;   // V-tile: rows of 64 elems, 8 lanes/row
  const int nkt = qb / 64 + 1;
  for (int kt = 0; kt < nkt; ++kt) {
    const int kv0 = kt * 64;
    if (kt) __syncthreads();
#pragma unroll
    for (int i = 0; i < 4; ++i) {
      int c = wid * 4 + i;
      int rowK = c * 4 + rK;
      gload_lds16(qkv + (size_t)(kv0 + rowK) * 6144 + 2048 + h * 128 + ((sK ^ (rowK & 7)) * 8),
                  lsK + c * 512);
      int rowV = c * 8 + rV;
      gload_lds16(vT + ((size_t)h * 128 + rowV) * 2048 + kv0 + ((sV ^ (rowV & 7)) * 8),
                  lsV + c * 512);
    }
    __syncthreads();

    // QK^T (S tile 16x64)
    f32x4 sc[4];
#pragma unroll
    for (int nt = 0; nt < 4; ++nt) sc[nt] = (f32x4){0.f, 0.f, 0.f, 0.f};
#pragma unroll
    for (int ks = 0; ks < 4; ++ks) {
#pragma unroll
      for (int nt = 0; nt < 4; ++nt) {
        int kvr = nt * 16 + lq;
        short8 kf = *(const short8*)((const char*)lsK + kvr * 256 +
                                     ((ks * 64 + lk * 16) ^ ((kvr & 7) << 4)));
        sc[nt] = mfma16(qf[ks], kf, sc[nt]);
      }
    }
    // scale + causal mask + row max
    float rmax[4] = {-INFINITY, -INFINITY, -INFINITY, -INFINITY};
#pragma unroll
    for (int nt = 0; nt < 4; ++nt) {
      int kv = kv0 + nt * 16 + lq;
#pragma unroll
      for (int r = 0; r < 4; ++r) {
        int qrow = qw + lk * 4 + r;
        float s = (kv <= qrow) ? sc[nt][r] * 0.08838834764831845f : -INFINITY;
        sc[nt][r] = s;
        rmax[r] = fmaxf(rmax[r], s);
      }
    }
#pragma unroll
    for (int r = 0; r < 4; ++r)
#pragma unroll
      for (int w = 1; w < 16; w <<= 1) rmax[r] = fmaxf(rmax[r], __shfl_xor(rmax[r], w));
    float alpha[4], rsum[4];
#pragma unroll
    for (int r = 0; r < 4; ++r) {
      float mn = fmaxf(mreg[r], rmax[r]);
      alpha[r] = __expf(mreg[r] - mn);
      mreg[r] = mn;
      rsum[r] = 0.f;
    }
    u16* P = &lsP[wid][0];
#pragma unroll
    for (int nt = 0; nt < 4; ++nt) {
#pragma unroll
      for (int r = 0; r < 4; ++r) {
        float p = __expf(sc[nt][r] - mreg[r]);
        rsum[r] += p;
        int prow = lk * 4 + r, pcol = nt * 16 + lq;
        *(u16*)((char*)P + prow * 128 + ((pcol * 2) ^ ((prow & 7) << 4))) = f2bf(p);
      }
    }
#pragma unroll
    for (int r = 0; r < 4; ++r) {
#pragma unroll
      for (int w = 1; w < 16; w <<= 1) rsum[r] += __shfl_xor(rsum[r], w);
      lreg[r] = lreg[r] * alpha[r] + rsum[r];
    }
#pragma unroll
    for (int dt = 0; dt < 8; ++dt)
#pragma unroll
      for (int r = 0; r < 4; ++r) o[dt][r] *= alpha[r];
    // PV
#pragma unroll
    for (int kk = 0; kk < 2; ++kk) {
      short8 pa = *(const short8*)((const char*)P + lq * 128 +
                                   ((kk * 64 + lk * 16) ^ ((lq & 7) << 4)));
#pragma unroll
      for (int dt = 0; dt < 8; ++dt) {
        int dr = dt * 16 + lq;
        short8 vf = *(const short8*)((const char*)lsV + dr * 128 +
                                     ((kk * 64 + lk * 16) ^ ((dr & 7) << 4)));
        o[dt] = mfma16(pa, vf, o[dt]);
      }
    }
  }
  // epilogue
#pragma unroll
  for (int r = 0; r < 4; ++r) {
    float inv = 1.f / lreg[r];
    int row = qw + lk * 4 + r;
    u16* op = attnout + (size_t)row * 2048 + h * 128 + lq;
#pragma unroll
    for (int dt = 0; dt < 8; ++dt) op[dt * 16] = f2bf(o[dt][r] * inv);
  }
}

extern "C" void kernel_launch(void* const* d_in, const int* in_sizes, int n_in,
                              void* d_out, int out_size, void* d_ws, size_t ws_size,
                              hipStream_t stream) {
  (void)in_sizes; (void)n_in; (void)out_size; (void)ws_size;
  const float* x    = (const float*)d_in[0];
  const float* ln1g = (const float*)d_in[1];
  const float* ln1b = (const float*)d_in[2];
  const float* Wq   = (const float*)d_in[3];
  const float* Wk   = (const float*)d_in[4];
  const float* Wv   = (const float*)d_in[5];
  const float* Wp   = (const float*)d_in[6];
  const float* bp   = (const float*)d_in[7];
  const float* ln2g = (const float*)d_in[8];
  const float* ln2b = (const float*)d_in[9];
  const float* W1   = (const float*)d_in[10];
  const float* b1   = (const float*)d_in[11];
  const float* W2   = (const float*)d_in[12];
  const float* b2   = (const float*)d_in[13];
  float* out = (float*)d_out;
  char* ws = (char*)d_ws;

  u16* wqkvT = (u16*)(ws + 0);          // [6144][2048] bf16  (25165824 B)
  u16* hbuf  = (u16*)(ws + 25165824);   // [2048][2048] bf16
  u16* wpT   = (u16*)(ws + 33554432);   // [2048][2048] bf16
  u16* w1T   = (u16*)(ws + 41943040);   // [8192][2048] bf16
  u16* w2T   = (u16*)(ws + 75497472);   // [2048][8192] bf16
  u16* qkv   = (u16*)(ws + 109051904);  // [2048][6144] bf16
  u16* vT    = (u16*)(ws + 134217728);  // [16][128][2048] bf16
  u16* attn  = (u16*)(ws + 142606336);  // [2048][2048] bf16
  float* x1  = (float*)(ws + 150994944);// [2048][2048] f32
  u16* g     = (u16*)(ws + 167772160);  // [2048][2048] bf16
  u16* ff1   = (u16*)(ws + 0);          // [2048][8192] bf16, aliases wqkvT+hbuf (dead by then)

  dim3 b256(256);
  transpose_cast<<<dim3(32, 32), b256, 0, stream>>>(Wq, wqkvT, 2048, 2048);
  transpose_cast<<<dim3(32, 32), b256, 0, stream>>>(Wk, wqkvT + 2048 * 2048, 2048, 2048);
  transpose_cast<<<dim3(32, 32), b256, 0, stream>>>(Wv, wqkvT + 4096 * 2048, 2048, 2048);
  transpose_cast<<<dim3(32, 32), b256, 0, stream>>>(Wp, wpT, 2048, 2048);
  transpose_cast<<<dim3(128, 32), b256, 0, stream>>>(W1, w1T, 2048, 8192);
  transpose_cast<<<dim3(32, 128), b256, 0, stream>>>(W2, w2T, 8192, 2048);
  ln_kernel<<<2048, b256, 0, stream>>>(x, ln1g, ln1b, hbuf);
  gemm_kernel<0><<<dim3(48, 16), b256, 0, stream>>>(hbuf, wqkvT, 2048, 6144, 2048,
                                                    nullptr, qkv, nullptr, nullptr, nullptr);
  transpose_v<<<dim3(32, 2, 16), b256, 0, stream>>>(qkv, vT);
  attn_kernel<<<dim3(32, 16), b256, 0, stream>>>(qkv, vT, attn);
  gemm_kernel<1><<<dim3(16, 16), b256, 0, stream>>>(attn, wpT, 2048, 2048, 2048,
                                                    x1, nullptr, bp, x, nullptr);
  ln_kernel<<<2048, b256, 0, stream>>>(x1, ln2g, ln2b, g);
  gemm_kernel<2><<<dim3(64, 16), b256, 0, stream>>>(g, w1T, 2048, 8192, 2048,
                                                    nullptr, ff1, b1, nullptr, nullptr);
  gemm_kernel<3><<<dim3(16, 16), b256, 0, stream>>>(ff1, w2T, 2048, 2048, 8192,
                                                    out, nullptr, b2, x1, g);
}

// Round 2
// 456.302 us; speedup vs baseline: 1.1471x; 1.1471x over previous
//
#include <hip/hip_runtime.h>
#include <math.h>

typedef unsigned int u32;
typedef unsigned short u16;
typedef __attribute__((ext_vector_type(8))) short short8;
typedef __attribute__((ext_vector_type(4))) float f32x4;

__device__ __forceinline__ u16 f2bf(float f) {
  u32 u = __builtin_bit_cast(u32, f);
  u += 0x7FFFu + ((u >> 16) & 1u);
  return (u16)(u >> 16);
}
__device__ __forceinline__ float bf2f(u16 h) {
  u32 u = ((u32)h) << 16;
  return __builtin_bit_cast(float, u);
}
__device__ __forceinline__ void gload_lds16(const void* g, void* l) {
  __builtin_amdgcn_global_load_lds((const __attribute__((address_space(1))) u32*)g,
                                   (__attribute__((address_space(3))) u32*)l, 16, 0, 0);
}
__device__ __forceinline__ f32x4 mfma16(short8 a, short8 b, f32x4 c) {
  return __builtin_amdgcn_mfma_f32_16x16x32_bf16(a, b, c, 0, 0, 0);
}

// ---------------- transpose+cast: src fp32 [K][N] -> dst bf16 [N][K] ----------------
__global__ __launch_bounds__(256) void transpose_cast(const float* __restrict__ src,
                                                      u16* __restrict__ dst, int K, int N) {
  __shared__ __attribute__((aligned(16))) u16 tile[64][72];
  const int n0 = blockIdx.x * 64, k0 = blockIdx.y * 64;
  const int t = threadIdx.x;
  const int tr = t >> 4;          // 0..15
  const int tc4 = (t & 15) * 4;   // 0..60
#pragma unroll
  for (int p = 0; p < 4; ++p) {
    int row = p * 16 + tr;  // k-local
    const float4 v = *(const float4*)(src + (size_t)(k0 + row) * N + n0 + tc4);
    tile[tc4 + 0][row] = f2bf(v.x);
    tile[tc4 + 1][row] = f2bf(v.y);
    tile[tc4 + 2][row] = f2bf(v.z);
    tile[tc4 + 3][row] = f2bf(v.w);
  }
  __syncthreads();
  const int nr = t >> 2;          // 0..63
  const int kc = (t & 3) * 16;    // 0,16,32,48
  u16* d = dst + (size_t)(n0 + nr) * K + k0 + kc;
  *(short8*)(d) = *(const short8*)&tile[nr][kc];
  *(short8*)(d + 8) = *(const short8*)&tile[nr][kc + 8];
}

// ---------------- transpose V out of qkv: -> vT[h][d][kv] ----------------
__global__ __launch_bounds__(256) void transpose_v(const u16* __restrict__ qkv,
                                                   u16* __restrict__ vT) {
  __shared__ __attribute__((aligned(16))) u16 tile[64][72];
  const int kv0 = blockIdx.x * 64, d0 = blockIdx.y * 64, h = blockIdx.z;
  const int t = threadIdx.x;
  const int tr = t >> 3;         // 0..31
  const int tc8 = (t & 7) * 8;
#pragma unroll
  for (int p = 0; p < 2; ++p) {
    int row = p * 32 + tr;  // kv-local
    short8 v = *(const short8*)(qkv + (size_t)(kv0 + row) * 6144 + 4096 + h * 128 + d0 + tc8);
#pragma unroll
    for (int j = 0; j < 8; ++j) tile[tc8 + j][row] = (u16)v[j];
  }
  __syncthreads();
  const int dr = t >> 2;          // 0..63
  const int kc = (t & 3) * 16;
  u16* dst = vT + ((size_t)h * 128 + d0 + dr) * 2048 + kv0 + kc;
  *(short8*)dst = *(const short8*)&tile[dr][kc];
  *(short8*)(dst + 8) = *(const short8*)&tile[dr][kc + 8];
}

// ---------------- LayerNorm: fp32 [2048 rows][2048] -> bf16 ----------------
__global__ __launch_bounds__(256) void ln_kernel(const float* __restrict__ x,
                                                 const float* __restrict__ gw,
                                                 const float* __restrict__ bw,
                                                 u16* __restrict__ out) {
  const int row = blockIdx.x, t = threadIdx.x;
  const float* xr = x + (size_t)row * 2048;
  const float4 v0 = *(const float4*)(xr + t * 8);
  const float4 v1 = *(const float4*)(xr + t * 8 + 4);
  float s = v0.x + v0.y + v0.z + v0.w + v1.x + v1.y + v1.z + v1.w;
  float q = v0.x * v0.x + v0.y * v0.y + v0.z * v0.z + v0.w * v0.w +
            v1.x * v1.x + v1.y * v1.y + v1.z * v1.z + v1.w * v1.w;
#pragma unroll
  for (int w = 32; w; w >>= 1) { s += __shfl_xor(s, w); q += __shfl_xor(q, w); }
  __shared__ float rs[4], rq[4];
  const int wid = t >> 6, lane = t & 63;
  if (!lane) { rs[wid] = s; rq[wid] = q; }
  __syncthreads();
  s = rs[0] + rs[1] + rs[2] + rs[3];
  q = rq[0] + rq[1] + rq[2] + rq[3];
  const float mu = s * (1.f / 2048.f);
  const float var = q * (1.f / 2048.f) - mu * mu;
  const float rstd = rsqrtf(var + 1e-5f);
  const float4 g0 = *(const float4*)(gw + t * 8);
  const float4 g1 = *(const float4*)(gw + t * 8 + 4);
  const float4 b0 = *(const float4*)(bw + t * 8);
  const float4 b1 = *(const float4*)(bw + t * 8 + 4);
  short8 o;
  o[0] = (short)f2bf((v0.x - mu) * rstd * g0.x + b0.x);
  o[1] = (short)f2bf((v0.y - mu) * rstd * g0.y + b0.y);
  o[2] = (short)f2bf((v0.z - mu) * rstd * g0.z + b0.z);
  o[3] = (short)f2bf((v0.w - mu) * rstd * g0.w + b0.w);
  o[4] = (short)f2bf((v1.x - mu) * rstd * g1.x + b1.x);
  o[5] = (short)f2bf((v1.y - mu) * rstd * g1.y + b1.y);
  o[6] = (short)f2bf((v1.z - mu) * rstd * g1.z + b1.z);
  o[7] = (short)f2bf((v1.w - mu) * rstd * g1.w + b1.w);
  *(short8*)(out + (size_t)row * 2048 + t * 8) = o;
}

// ---------------- GEMM: C[M][N] = A[M][K](bf16) @ Bt[N][K]^T (bf16), epilogues ----------------
// EPI 0: out bf16 plain                  (QKV proj)
// EPI 1: out f32 = v+bias+res1           (unused now)
// EPI 2: out bf16 = gelu(v+bias)         (FF1)
// EPI 3: out f32 = v+bias+res1+bf(res2)  (unused now)
// EPI 4: f32 partial to pA/pB selected by blockIdx.z (split-K)
template <int EPI>
__global__ __launch_bounds__(256) void gemm_kernel(const u16* __restrict__ A,
                                                   const u16* __restrict__ Bt,
                                                   int M, int N, int K, int Kc,
                                                   float* __restrict__ outF,
                                                   u16* __restrict__ outB,
                                                   const float* __restrict__ bias,
                                                   const float* __restrict__ res1,
                                                   const u16* __restrict__ res2,
                                                   float* __restrict__ pA,
                                                   float* __restrict__ pB) {
  __shared__ __attribute__((aligned(16))) u16 lsA[128 * 64];
  __shared__ __attribute__((aligned(16))) u16 lsB[128 * 64];
  const int m0 = blockIdx.y * 128, n0 = blockIdx.x * 128;
  const int tid = threadIdx.x, wid = tid >> 6, lane = tid & 63;
  const int wm = (wid >> 1) * 64, wn = (wid & 1) * 64;
  const int lq = lane & 15, lk = lane >> 4;
  const int rIn = lane >> 3, sIn = lane & 7;  // stage: 8 lanes/row of 64 elems
  const int kStart = blockIdx.z * Kc;
  f32x4 acc[4][4] = {};

  for (int kt = kStart; kt < kStart + Kc; kt += 64) {
    if (kt != kStart) __syncthreads();
#pragma unroll
    for (int i = 0; i < 4; ++i) {
      int c = wid * 4 + i;
      int row = c * 8 + rIn;
      int scol = (sIn ^ (row & 7)) * 8;
      gload_lds16(A + (size_t)(m0 + row) * K + kt + scol, lsA + c * 512);
      gload_lds16(Bt + (size_t)(n0 + row) * K + kt + scol, lsB + c * 512);
    }
    __syncthreads();
#pragma unroll
    for (int kk = 0; kk < 2; ++kk) {
      short8 af[4], bfr[4];
#pragma unroll
      for (int i = 0; i < 4; ++i) {
        int ra = wm + i * 16 + lq;
        af[i] = *(const short8*)((const char*)lsA + ra * 128 +
                                 ((kk * 64 + lk * 16) ^ ((ra & 7) << 4)));
        int rb = wn + i * 16 + lq;
        bfr[i] = *(const short8*)((const char*)lsB + rb * 128 +
                                  ((kk * 64 + lk * 16) ^ ((rb & 7) << 4)));
      }
#pragma unroll
      for (int mi = 0; mi < 4; ++mi)
#pragma unroll
        for (int ni = 0; ni < 4; ++ni)
          acc[mi][ni] = mfma16(af[mi], bfr[ni], acc[mi][ni]);
    }
  }
  float* pp = nullptr;
  if (EPI == 4) {
    pp = (blockIdx.z < 2) ? pA : pB;
    pp += (size_t)(blockIdx.z & 1) * ((size_t)M * N);
  }
#pragma unroll
  for (int mi = 0; mi < 4; ++mi) {
#pragma unroll
    for (int ni = 0; ni < 4; ++ni) {
      const int col = n0 + wn + ni * 16 + lq;
#pragma unroll
      for (int r = 0; r < 4; ++r) {
        const int row = m0 + wm + mi * 16 + lk * 4 + r;
        const size_t idx = (size_t)row * N + col;
        float v = acc[mi][ni][r];
        if (EPI == 0) {
          outB[idx] = f2bf(v);
        } else if (EPI == 1) {
          outF[idx] = v + bias[col] + res1[idx];
        } else if (EPI == 2) {
          float xg = v + bias[col];
          outB[idx] = f2bf(0.5f * xg * (1.f + erff(xg * 0.70710678118654752f)));
        } else if (EPI == 3) {
          outF[idx] = v + bias[col] + res1[idx] + bf2f(res2[idx]);
        } else {
          pp[idx] = v;
        }
      }
    }
  }
}

// ---------------- split-K reduce: out = sum(partials) + bias + res1 (+ bf(res2)) ----------------
// N must be a power of two (2048 here). Each thread handles 4 consecutive floats.
template <int NS, int RES2>
__global__ __launch_bounds__(256) void reduce_kernel(const float* __restrict__ pA,
                                                     const float* __restrict__ pB,
                                                     const float* __restrict__ bias,
                                                     const float* __restrict__ res1,
                                                     const u16* __restrict__ res2,
                                                     float* __restrict__ out,
                                                     int MN, int N) {
  const int i = (blockIdx.x * 256 + threadIdx.x) * 4;
  if (i >= MN) return;
  float4 s = *(const float4*)(pA + i);
  {
    const float4 t = *(const float4*)(pA + MN + i);
    s.x += t.x; s.y += t.y; s.z += t.z; s.w += t.w;
  }
  if (NS == 4) {
    const float4 t0 = *(const float4*)(pB + i);
    const float4 t1 = *(const float4*)(pB + MN + i);
    s.x += t0.x + t1.x; s.y += t0.y + t1.y; s.z += t0.z + t1.z; s.w += t0.w + t1.w;
  }
  const int col = i & (N - 1);
  const float4 bv = *(const float4*)(bias + col);
  const float4 r1 = *(const float4*)(res1 + i);
  float4 o;
  o.x = s.x + bv.x + r1.x;
  o.y = s.y + bv.y + r1.y;
  o.z = s.z + bv.z + r1.z;
  o.w = s.w + bv.w + r1.w;
  if (RES2) {
    const u16* r2 = res2 + i;
    o.x += bf2f(r2[0]); o.y += bf2f(r2[1]); o.z += bf2f(r2[2]); o.w += bf2f(r2[3]);
  }
  *(float4*)(out + i) = o;
}

// ---------------- flash attention (causal), 4 waves x 16 q-rows, KVBLK=64 ----------------
__global__ __launch_bounds__(256) void attn_kernel(const u16* __restrict__ qkv,
                                                   const u16* __restrict__ vT,
                                                   u16* __restrict__ attnout) {
  __shared__ __attribute__((aligned(16))) u16 lsK[64 * 128];   // [kv][d], swizzled
  __shared__ __attribute__((aligned(16))) u16 lsV[128 * 64];   // [d][kv], swizzled
  __shared__ __attribute__((aligned(16))) u16 lsP[4][16 * 64]; // per-wave P, swizzled
  const int h = blockIdx.y;
  const int qb = blockIdx.x * 64;
  const int tid = threadIdx.x, wid = tid >> 6, lane = tid & 63;
  const int lq = lane & 15, lk = lane >> 4;
  const int qw = qb + wid * 16;

  short8 qf[4];
  {
    const u16* qp = qkv + (size_t)(qw + lq) * 6144 + h * 128;
#pragma unroll
    for (int ks = 0; ks < 4; ++ks) qf[ks] = *(const short8*)(qp + ks * 32 + lk * 8);
  }
  float mreg[4], lreg[4];
  f32x4 o[8];
#pragma unroll
  for (int r = 0; r < 4; ++r) { mreg[r] = -INFINITY; lreg[r] = 0.f; }
#pragma unroll
  for (int dt = 0; dt < 8; ++dt) o[dt] = (f32x4){0.f, 0.f, 0.f, 0.f};

  const int rK = lane >> 4, sK = lane & 15;  // K-tile: rows of 128 elems, 16 lanes/row
  const int rV = lane >> 3, sV = lane & 7;   // V-tile: rows of 64 elems, 8 lanes/row
  const int nkt = qb / 64 + 1;
  for (int kt = 0; kt < nkt; ++kt) {
    const int kv0 = kt * 64;
    if (kt) __syncthreads();
#pragma unroll
    for (int i = 0; i < 4; ++i) {
      int c = wid * 4 + i;
      int rowK = c * 4 + rK;
      gload_lds16(qkv + (size_t)(kv0 + rowK) * 6144 + 2048 + h * 128 + ((sK ^ (rowK & 7)) * 8),
                  lsK + c * 512);
      int rowV = c * 8 + rV;
      gload_lds16(vT + ((size_t)h * 128 + rowV) * 2048 + kv0 + ((sV ^ (rowV & 7)) * 8),
                  lsV + c * 512);
    }
    __syncthreads();

    // QK^T (S tile 16x64)
    f32x4 sc[4];
#pragma unroll
    for (int nt = 0; nt < 4; ++nt) sc[nt] = (f32x4){0.f, 0.f, 0.f, 0.f};
#pragma unroll
    for (int ks = 0; ks < 4; ++ks) {
#pragma unroll
      for (int nt = 0; nt < 4; ++nt) {
        int kvr = nt * 16 + lq;
        short8 kf = *(const short8*)((const char*)lsK + kvr * 256 +
                                     ((ks * 64 + lk * 16) ^ ((kvr & 7) << 4)));
        sc[nt] = mfma16(qf[ks], kf, sc[nt]);
      }
    }
    // scale + causal mask + row max
    float rmax[4] = {-INFINITY, -INFINITY, -INFINITY, -INFINITY};
#pragma unroll
    for (int nt = 0; nt < 4; ++nt) {
      int kv = kv0 + nt * 16 + lq;
#pragma unroll
      for (int r = 0; r < 4; ++r) {
        int qrow = qw + lk * 4 + r;
        float s = (kv <= qrow) ? sc[nt][r] * 0.08838834764831845f : -INFINITY;
        sc[nt][r] = s;
        rmax[r] = fmaxf(rmax[r], s);
      }
    }
#pragma unroll
    for (int r = 0; r < 4; ++r)
#pragma unroll
      for (int w = 1; w < 16; w <<= 1) rmax[r] = fmaxf(rmax[r], __shfl_xor(rmax[r], w));
    float alpha[4], rsum[4];
#pragma unroll
    for (int r = 0; r < 4; ++r) {
      float mn = fmaxf(mreg[r], rmax[r]);
      alpha[r] = __expf(mreg[r] - mn);
      mreg[r] = mn;
      rsum[r] = 0.f;
    }
    u16* P = &lsP[wid][0];
#pragma unroll
    for (int nt = 0; nt < 4; ++nt) {
#pragma unroll
      for (int r = 0; r < 4; ++r) {
        float p = __expf(sc[nt][r] - mreg[r]);
        rsum[r] += p;
        int prow = lk * 4 + r, pcol = nt * 16 + lq;
        *(u16*)((char*)P + prow * 128 + ((pcol * 2) ^ ((prow & 7) << 4))) = f2bf(p);
      }
    }
#pragma unroll
    for (int r = 0; r < 4; ++r) {
#pragma unroll
      for (int w = 1; w < 16; w <<= 1) rsum[r] += __shfl_xor(rsum[r], w);
      lreg[r] = lreg[r] * alpha[r] + rsum[r];
    }
#pragma unroll
    for (int dt = 0; dt < 8; ++dt)
#pragma unroll
      for (int r = 0; r < 4; ++r) o[dt][r] *= alpha[r];
    // PV
#pragma unroll
    for (int kk = 0; kk < 2; ++kk) {
      short8 pa = *(const short8*)((const char*)P + lq * 128 +
                                   ((kk * 64 + lk * 16) ^ ((lq & 7) << 4)));
#pragma unroll
      for (int dt = 0; dt < 8; ++dt) {
        int dr = dt * 16 + lq;
        short8 vf = *(const short8*)((const char*)lsV + dr * 128 +
                                     ((kk * 64 + lk * 16) ^ ((dr & 7) << 4)));
        o[dt] = mfma16(pa, vf, o[dt]);
      }
    }
  }
  // epilogue
#pragma unroll
  for (int r = 0; r < 4; ++r) {
    float inv = 1.f / lreg[r];
    int row = qw + lk * 4 + r;
    u16* op = attnout + (size_t)row * 2048 + h * 128 + lq;
#pragma unroll
    for (int dt = 0; dt < 8; ++dt) op[dt * 16] = f2bf(o[dt][r] * inv);
  }
}

extern "C" void kernel_launch(void* const* d_in, const int* in_sizes, int n_in,
                              void* d_out, int out_size, void* d_ws, size_t ws_size,
                              hipStream_t stream) {
  (void)in_sizes; (void)n_in; (void)out_size; (void)ws_size;
  const float* x    = (const float*)d_in[0];
  const float* ln1g = (const float*)d_in[1];
  const float* ln1b = (const float*)d_in[2];
  const float* Wq   = (const float*)d_in[3];
  const float* Wk   = (const float*)d_in[4];
  const float* Wv   = (const float*)d_in[5];
  const float* Wp   = (const float*)d_in[6];
  const float* bp   = (const float*)d_in[7];
  const float* ln2g = (const float*)d_in[8];
  const float* ln2b = (const float*)d_in[9];
  const float* W1   = (const float*)d_in[10];
  const float* b1   = (const float*)d_in[11];
  const float* W2   = (const float*)d_in[12];
  const float* b2   = (const float*)d_in[13];
  float* out = (float*)d_out;
  char* ws = (char*)d_ws;

  u16* wqkvT = (u16*)(ws + 0);          // [6144][2048] bf16  (24 MB)
  u16* hbuf  = (u16*)(ws + 25165824);   // [2048][2048] bf16  (8 MB)
  u16* wpT   = (u16*)(ws + 33554432);   // [2048][2048] bf16  (8 MB)
  u16* w1T   = (u16*)(ws + 41943040);   // [8192][2048] bf16  (32 MB)
  u16* w2T   = (u16*)(ws + 75497472);   // [2048][8192] bf16  (32 MB)
  u16* qkv   = (u16*)(ws + 109051904);  // [2048][6144] bf16  (24 MB)
  u16* vT    = (u16*)(ws + 134217728);  // [16][128][2048] bf16 (8 MB)
  u16* attn  = (u16*)(ws + 142606336);  // [2048][2048] bf16  (8 MB)
  float* x1  = (float*)(ws + 150994944);// [2048][2048] f32   (16 MB)
  u16* g     = (u16*)(ws + 167772160);  // [2048][2048] bf16  (8 MB)
  u16* ff1   = (u16*)(ws + 0);          // [2048][8192] bf16, aliases wqkvT+hbuf (dead)
  // proj split-K partials: 2 x 16 MB over dead qkv+vT region
  float* projP = (float*)(ws + 109051904);
  // FF2 split-K partials: 2 x 16 MB over dead wpT+w1T, 2 x 16 MB over dead qkv+vT
  float* ffPA = (float*)(ws + 33554432);
  float* ffPB = (float*)(ws + 109051904);

  dim3 b256(256);
  transpose_cast<<<dim3(32, 32), b256, 0, stream>>>(Wq, wqkvT, 2048, 2048);
  transpose_cast<<<dim3(32, 32), b256, 0, stream>>>(Wk, wqkvT + 2048 * 2048, 2048, 2048);
  transpose_cast<<<dim3(32, 32), b256, 0, stream>>>(Wv, wqkvT + 4096 * 2048, 2048, 2048);
  transpose_cast<<<dim3(32, 32), b256, 0, stream>>>(Wp, wpT, 2048, 2048);
  transpose_cast<<<dim3(128, 32), b256, 0, stream>>>(W1, w1T, 2048, 8192);
  transpose_cast<<<dim3(32, 128), b256, 0, stream>>>(W2, w2T, 8192, 2048);
  ln_kernel<<<2048, b256, 0, stream>>>(x, ln1g, ln1b, hbuf);
  gemm_kernel<0><<<dim3(48, 16), b256, 0, stream>>>(hbuf, wqkvT, 2048, 6144, 2048, 2048,
                                                    nullptr, qkv, nullptr, nullptr, nullptr,
                                                    nullptr, nullptr);
  transpose_v<<<dim3(32, 2, 16), b256, 0, stream>>>(qkv, vT);
  attn_kernel<<<dim3(32, 16), b256, 0, stream>>>(qkv, vT, attn);
  // attn out proj, split-K=2 (K=2048 -> 2x1024), partials then fused reduce (+bp +x)
  gemm_kernel<4><<<dim3(16, 16, 2), b256, 0, stream>>>(attn, wpT, 2048, 2048, 2048, 1024,
                                                       nullptr, nullptr, nullptr, nullptr,
                                                       nullptr, projP, nullptr);
  reduce_kernel<2, 0><<<4096, b256, 0, stream>>>(projP, nullptr, bp, x, nullptr, x1,
                                                 4194304, 2048);
  ln_kernel<<<2048, b256, 0, stream>>>(x1, ln2g, ln2b, g);
  gemm_kernel<2><<<dim3(64, 16), b256, 0, stream>>>(g, w1T, 2048, 8192, 2048, 2048,
                                                    nullptr, ff1, b1, nullptr, nullptr,
                                                    nullptr, nullptr);
  // FF2, split-K=4 (K=8192 -> 4x2048), partials then fused reduce (+b2 +x1 +g)
  gemm_kernel<4><<<dim3(16, 16, 4), b256, 0, stream>>>(ff1, w2T, 2048, 2048, 8192, 2048,
                                                       nullptr, nullptr, nullptr, nullptr,
                                                       nullptr, ffPA, ffPB);
  reduce_kernel<4, 1><<<4096, b256, 0, stream>>>(ffPA, ffPB, b2, x1, g, out,
                                                 4194304, 2048);
}

// Round 3
// 444.650 us; speedup vs baseline: 1.1771x; 1.0262x over previous
//
#include <hip/hip_runtime.h>
#include <math.h>

typedef unsigned int u32;
typedef unsigned short u16;
typedef __attribute__((ext_vector_type(8))) short short8;
typedef __attribute__((ext_vector_type(4))) float f32x4;

__device__ __forceinline__ u16 f2bf(float f) {
  u32 u = __builtin_bit_cast(u32, f);
  u += 0x7FFFu + ((u >> 16) & 1u);
  return (u16)(u >> 16);
}
__device__ __forceinline__ float bf2f(u16 h) {
  u32 u = ((u32)h) << 16;
  return __builtin_bit_cast(float, u);
}
__device__ __forceinline__ void gload_lds16(const void* g, void* l) {
  __builtin_amdgcn_global_load_lds((const __attribute__((address_space(1))) u32*)g,
                                   (__attribute__((address_space(3))) u32*)l, 16, 0, 0);
}
__device__ __forceinline__ f32x4 mfma16(short8 a, short8 b, f32x4 c) {
  return __builtin_amdgcn_mfma_f32_16x16x32_bf16(a, b, c, 0, 0, 0);
}

// ---------------- transpose+cast: src fp32 [K][N] -> dst bf16 [N][K] ----------------
__global__ __launch_bounds__(256) void transpose_cast(const float* __restrict__ src,
                                                      u16* __restrict__ dst, int K, int N) {
  __shared__ __attribute__((aligned(16))) u16 tile[64][72];
  const int n0 = blockIdx.x * 64, k0 = blockIdx.y * 64;
  const int t = threadIdx.x;
  const int tr = t >> 4;          // 0..15
  const int tc4 = (t & 15) * 4;   // 0..60
#pragma unroll
  for (int p = 0; p < 4; ++p) {
    int row = p * 16 + tr;  // k-local
    const float4 v = *(const float4*)(src + (size_t)(k0 + row) * N + n0 + tc4);
    tile[tc4 + 0][row] = f2bf(v.x);
    tile[tc4 + 1][row] = f2bf(v.y);
    tile[tc4 + 2][row] = f2bf(v.z);
    tile[tc4 + 3][row] = f2bf(v.w);
  }
  __syncthreads();
  const int nr = t >> 2;          // 0..63
  const int kc = (t & 3) * 16;    // 0,16,32,48
  u16* d = dst + (size_t)(n0 + nr) * K + k0 + kc;
  *(short8*)(d) = *(const short8*)&tile[nr][kc];
  *(short8*)(d + 8) = *(const short8*)&tile[nr][kc + 8];
}

// ---------------- transpose V out of qkv: -> vT[h][d][kv] ----------------
__global__ __launch_bounds__(256) void transpose_v(const u16* __restrict__ qkv,
                                                   u16* __restrict__ vT) {
  __shared__ __attribute__((aligned(16))) u16 tile[64][72];
  const int kv0 = blockIdx.x * 64, d0 = blockIdx.y * 64, h = blockIdx.z;
  const int t = threadIdx.x;
  const int tr = t >> 3;         // 0..31
  const int tc8 = (t & 7) * 8;
#pragma unroll
  for (int p = 0; p < 2; ++p) {
    int row = p * 32 + tr;  // kv-local
    short8 v = *(const short8*)(qkv + (size_t)(kv0 + row) * 6144 + 4096 + h * 128 + d0 + tc8);
#pragma unroll
    for (int j = 0; j < 8; ++j) tile[tc8 + j][row] = (u16)v[j];
  }
  __syncthreads();
  const int dr = t >> 2;          // 0..63
  const int kc = (t & 3) * 16;
  u16* dst = vT + ((size_t)h * 128 + d0 + dr) * 2048 + kv0 + kc;
  *(short8*)dst = *(const short8*)&tile[dr][kc];
  *(short8*)(dst + 8) = *(const short8*)&tile[dr][kc + 8];
}

// ---------------- LayerNorm: fp32 [2048 rows][2048] -> bf16 ----------------
__global__ __launch_bounds__(256) void ln_kernel(const float* __restrict__ x,
                                                 const float* __restrict__ gw,
                                                 const float* __restrict__ bw,
                                                 u16* __restrict__ out) {
  const int row = blockIdx.x, t = threadIdx.x;
  const float* xr = x + (size_t)row * 2048;
  const float4 v0 = *(const float4*)(xr + t * 8);
  const float4 v1 = *(const float4*)(xr + t * 8 + 4);
  float s = v0.x + v0.y + v0.z + v0.w + v1.x + v1.y + v1.z + v1.w;
  float q = v0.x * v0.x + v0.y * v0.y + v0.z * v0.z + v0.w * v0.w +
            v1.x * v1.x + v1.y * v1.y + v1.z * v1.z + v1.w * v1.w;
#pragma unroll
  for (int w = 32; w; w >>= 1) { s += __shfl_xor(s, w); q += __shfl_xor(q, w); }
  __shared__ float rs[4], rq[4];
  const int wid = t >> 6, lane = t & 63;
  if (!lane) { rs[wid] = s; rq[wid] = q; }
  __syncthreads();
  s = rs[0] + rs[1] + rs[2] + rs[3];
  q = rq[0] + rq[1] + rq[2] + rq[3];
  const float mu = s * (1.f / 2048.f);
  const float var = q * (1.f / 2048.f) - mu * mu;
  const float rstd = rsqrtf(var + 1e-5f);
  const float4 g0 = *(const float4*)(gw + t * 8);
  const float4 g1 = *(const float4*)(gw + t * 8 + 4);
  const float4 b0 = *(const float4*)(bw + t * 8);
  const float4 b1 = *(const float4*)(bw + t * 8 + 4);
  short8 o;
  o[0] = (short)f2bf((v0.x - mu) * rstd * g0.x + b0.x);
  o[1] = (short)f2bf((v0.y - mu) * rstd * g0.y + b0.y);
  o[2] = (short)f2bf((v0.z - mu) * rstd * g0.z + b0.z);
  o[3] = (short)f2bf((v0.w - mu) * rstd * g0.w + b0.w);
  o[4] = (short)f2bf((v1.x - mu) * rstd * g1.x + b1.x);
  o[5] = (short)f2bf((v1.y - mu) * rstd * g1.y + b1.y);
  o[6] = (short)f2bf((v1.z - mu) * rstd * g1.z + b1.z);
  o[7] = (short)f2bf((v1.w - mu) * rstd * g1.w + b1.w);
  *(short8*)(out + (size_t)row * 2048 + t * 8) = o;
}

// ---------------- GEMM v2: 256x128 tile, BK=64, 8 waves, triple-buffer counted-vmcnt ----
// C[M][N] = A[M][K] @ Bt[N][K]^T, all bf16 in, f32 acc.
// EPI 0: out bf16 plain              (QKV proj)
// EPI 2: out bf16 = gelu(v+bias)     (FF1)
// EPI 4: f32 partial at pA + z*M*N   (split-K)
// Schedule: 2 phases per K-tile (16 MFMA each); stage K-tile t+2 during t
// (never the buffer being read -> race-free by construction); boundary
// s_waitcnt vmcnt(6) keeps 1 K-tile (6 loads/wave) in flight, never drain-0.
template <int EPI>
__global__ __launch_bounds__(512, 2) void gemm2(const u16* __restrict__ A,
                                                const u16* __restrict__ Bt,
                                                int M, int N, int K, int Kc,
                                                u16* __restrict__ outB,
                                                const float* __restrict__ bias,
                                                float* __restrict__ pA) {
  // per buffer: A[256][64] (16384 u16) + B[128][64] (8192 u16) = 24576 u16
  __shared__ __attribute__((aligned(16))) u16 lds[3 * 24576];
  const int m0 = blockIdx.y * 256, n0 = blockIdx.x * 128;
  const int tid = threadIdx.x, wid = tid >> 6, lane = tid & 63;
  const int wr = wid >> 1, wc = wid & 1;       // wave grid 4M x 2N
  const int lq = lane & 15, lk = lane >> 4;
  const int kStart = blockIdx.z * Kc;
  const int NT = Kc / 64;

  // staging geometry: chunk c covers row c>>3, 16B col (c&7); source col
  // pre-swizzled so linear LDS + XOR-read reconstructs (both-sides involution).
  size_t aoff[4], boff[2];
#pragma unroll
  for (int s = 0; s < 4; ++s) {
    int c = s * 512 + tid;
    int row = c >> 3, col = ((c & 7) ^ (row & 7)) * 8;
    aoff[s] = (size_t)(m0 + row) * K + col;
  }
#pragma unroll
  for (int s = 0; s < 2; ++s) {
    int c = s * 512 + tid;
    int row = c >> 3, col = ((c & 7) ^ (row & 7)) * 8;
    boff[s] = (size_t)(n0 + row) * K + col;
  }
  const int dstc = wid * 512 + lane * 8;  // wave-uniform base + lane*16B

#define STAGE_A(s, t2) \
  gload_lds16(A + aoff[s] + (size_t)(kStart + (t2) * 64), \
              lds + ((t2) % 3) * 24576 + (s) * 4096 + dstc)
#define STAGE_B(s, t2) \
  gload_lds16(Bt + boff[s] + (size_t)(kStart + (t2) * 64), \
              lds + ((t2) % 3) * 24576 + 16384 + (s) * 4096 + dstc)

  // prologue: fully stage K-tiles 0 and 1 (NT >= 2 always here)
  STAGE_A(0, 0); STAGE_A(1, 0); STAGE_A(2, 0); STAGE_A(3, 0); STAGE_B(0, 0); STAGE_B(1, 0);
  STAGE_A(0, 1); STAGE_A(1, 1); STAGE_A(2, 1); STAGE_A(3, 1); STAGE_B(0, 1); STAGE_B(1, 1);
  asm volatile("s_waitcnt vmcnt(6)" ::: "memory");  // K-tile 0 complete
  __builtin_amdgcn_s_barrier();
  __builtin_amdgcn_sched_barrier(0);

  f32x4 acc[4][4] = {};
  int cur = 0;
  for (int t = 0; t < NT; ++t) {
    const char* bufA = (const char*)lds + cur * 49152;
    const char* bufB = bufA + 32768;
    const int t2 = t + 2;
    const bool st = t2 < NT;
    const int xorq = (lq & 7) << 4;
#pragma unroll
    for (int ph = 0; ph < 2; ++ph) {
      short8 af[4], bf[4];
#pragma unroll
      for (int mi = 0; mi < 4; ++mi) {
        int ar = wr * 64 + mi * 16 + lq;
        af[mi] = *(const short8*)(bufA + ar * 128 + ((ph * 64 + lk * 16) ^ xorq));
      }
#pragma unroll
      for (int ni = 0; ni < 4; ++ni) {
        int br = wc * 64 + ni * 16 + lq;
        bf[ni] = *(const short8*)(bufB + br * 128 + ((ph * 64 + lk * 16) ^ xorq));
      }
      if (st) {
        if (ph == 0) { STAGE_A(0, t2); STAGE_A(1, t2); STAGE_A(2, t2); }
        else         { STAGE_A(3, t2); STAGE_B(0, t2); STAGE_B(1, t2); }
      }
      __builtin_amdgcn_s_barrier();
      __builtin_amdgcn_s_setprio(1);
#pragma unroll
      for (int mi = 0; mi < 4; ++mi)
#pragma unroll
        for (int ni = 0; ni < 4; ++ni)
          acc[mi][ni] = mfma16(af[mi], bf[ni], acc[mi][ni]);
      __builtin_amdgcn_s_setprio(0);
      if (ph == 1) {
        if (st) asm volatile("s_waitcnt vmcnt(6)" ::: "memory");  // t+1 complete, t+2 in flight
        else    asm volatile("s_waitcnt vmcnt(0)" ::: "memory");  // tail drain
      }
      __builtin_amdgcn_s_barrier();
      __builtin_amdgcn_sched_barrier(0);
    }
    cur = (cur == 2) ? 0 : cur + 1;
  }
#undef STAGE_A
#undef STAGE_B

  // epilogue
  float* pp = nullptr;
  if (EPI == 4) pp = pA + (size_t)blockIdx.z * ((size_t)M * N);
#pragma unroll
  for (int mi = 0; mi < 4; ++mi) {
#pragma unroll
    for (int ni = 0; ni < 4; ++ni) {
      const int col = n0 + wc * 64 + ni * 16 + lq;
#pragma unroll
      for (int r = 0; r < 4; ++r) {
        const int row = m0 + wr * 64 + mi * 16 + lk * 4 + r;
        const size_t idx = (size_t)row * N + col;
        float v = acc[mi][ni][r];
        if (EPI == 0) {
          outB[idx] = f2bf(v);
        } else if (EPI == 2) {
          float xg = v + bias[col];
          outB[idx] = f2bf(0.5f * xg * (1.f + erff(xg * 0.70710678118654752f)));
        } else {
          pp[idx] = v;
        }
      }
    }
  }
}

// ---------------- split-K reduce: out = pA[0]+pA[1] + bias + res1 (+ bf(res2)) ----------
template <int RES2>
__global__ __launch_bounds__(256) void reduce_kernel(const float* __restrict__ pA,
                                                     const float* __restrict__ bias,
                                                     const float* __restrict__ res1,
                                                     const u16* __restrict__ res2,
                                                     float* __restrict__ out,
                                                     int MN, int N) {
  const int i = (blockIdx.x * 256 + threadIdx.x) * 4;
  if (i >= MN) return;
  float4 s = *(const float4*)(pA + i);
  {
    const float4 t = *(const float4*)(pA + MN + i);
    s.x += t.x; s.y += t.y; s.z += t.z; s.w += t.w;
  }
  const int col = i & (N - 1);
  const float4 bv = *(const float4*)(bias + col);
  const float4 r1 = *(const float4*)(res1 + i);
  float4 o;
  o.x = s.x + bv.x + r1.x;
  o.y = s.y + bv.y + r1.y;
  o.z = s.z + bv.z + r1.z;
  o.w = s.w + bv.w + r1.w;
  if (RES2) {
    const u16* r2 = res2 + i;
    o.x += bf2f(r2[0]); o.y += bf2f(r2[1]); o.z += bf2f(r2[2]); o.w += bf2f(r2[3]);
  }
  *(float4*)(out + i) = o;
}

// ---------------- flash attention (causal), 4 waves x 16 q-rows, KVBLK=64 ----------------
__global__ __launch_bounds__(256) void attn_kernel(const u16* __restrict__ qkv,
                                                   const u16* __restrict__ vT,
                                                   u16* __restrict__ attnout) {
  __shared__ __attribute__((aligned(16))) u16 lsK[64 * 128];   // [kv][d], swizzled
  __shared__ __attribute__((aligned(16))) u16 lsV[128 * 64];   // [d][kv], swizzled
  __shared__ __attribute__((aligned(16))) u16 lsP[4][16 * 64]; // per-wave P, swizzled
  const int h = blockIdx.y;
  const int qb = blockIdx.x * 64;
  const int tid = threadIdx.x, wid = tid >> 6, lane = tid & 63;
  const int lq = lane & 15, lk = lane >> 4;
  const int qw = qb + wid * 16;

  short8 qf[4];
  {
    const u16* qp = qkv + (size_t)(qw + lq) * 6144 + h * 128;
#pragma unroll
    for (int ks = 0; ks < 4; ++ks) qf[ks] = *(const short8*)(qp + ks * 32 + lk * 8);
  }
  float mreg[4], lreg[4];
  f32x4 o[8];
#pragma unroll
  for (int r = 0; r < 4; ++r) { mreg[r] = -INFINITY; lreg[r] = 0.f; }
#pragma unroll
  for (int dt = 0; dt < 8; ++dt) o[dt] = (f32x4){0.f, 0.f, 0.f, 0.f};

  const int rK = lane >> 4, sK = lane & 15;  // K-tile: rows of 128 elems, 16 lanes/row
  const int rV = lane >> 3, sV = lane & 7;   // V-tile: rows of 64 elems, 8 lanes/row
  const int nkt = qb / 64 + 1;
  for (int kt = 0; kt < nkt; ++kt) {
    const int kv0 = kt * 64;
    if (kt) __syncthreads();
#pragma unroll
    for (int i = 0; i < 4; ++i) {
      int c = wid * 4 + i;
      int rowK = c * 4 + rK;
      gload_lds16(qkv + (size_t)(kv0 + rowK) * 6144 + 2048 + h * 128 + ((sK ^ (rowK & 7)) * 8),
                  lsK + c * 512);
      int rowV = c * 8 + rV;
      gload_lds16(vT + ((size_t)h * 128 + rowV) * 2048 + kv0 + ((sV ^ (rowV & 7)) * 8),
                  lsV + c * 512);
    }
    __syncthreads();

    // QK^T (S tile 16x64)
    f32x4 sc[4];
#pragma unroll
    for (int nt = 0; nt < 4; ++nt) sc[nt] = (f32x4){0.f, 0.f, 0.f, 0.f};
#pragma unroll
    for (int ks = 0; ks < 4; ++ks) {
#pragma unroll
      for (int nt = 0; nt < 4; ++nt) {
        int kvr = nt * 16 + lq;
        short8 kf = *(const short8*)((const char*)lsK + kvr * 256 +
                                     ((ks * 64 + lk * 16) ^ ((kvr & 7) << 4)));
        sc[nt] = mfma16(qf[ks], kf, sc[nt]);
      }
    }
    // scale + causal mask + row max
    float rmax[4] = {-INFINITY, -INFINITY, -INFINITY, -INFINITY};
#pragma unroll
    for (int nt = 0; nt < 4; ++nt) {
      int kv = kv0 + nt * 16 + lq;
#pragma unroll
      for (int r = 0; r < 4; ++r) {
        int qrow = qw + lk * 4 + r;
        float s = (kv <= qrow) ? sc[nt][r] * 0.08838834764831845f : -INFINITY;
        sc[nt][r] = s;
        rmax[r] = fmaxf(rmax[r], s);
      }
    }
#pragma unroll
    for (int r = 0; r < 4; ++r)
#pragma unroll
      for (int w = 1; w < 16; w <<= 1) rmax[r] = fmaxf(rmax[r], __shfl_xor(rmax[r], w));
    float alpha[4], rsum[4];
#pragma unroll
    for (int r = 0; r < 4; ++r) {
      float mn = fmaxf(mreg[r], rmax[r]);
      alpha[r] = __expf(mreg[r] - mn);
      mreg[r] = mn;
      rsum[r] = 0.f;
    }
    u16* P = &lsP[wid][0];
#pragma unroll
    for (int nt = 0; nt < 4; ++nt) {
#pragma unroll
      for (int r = 0; r < 4; ++r) {
        float p = __expf(sc[nt][r] - mreg[r]);
        rsum[r] += p;
        int prow = lk * 4 + r, pcol = nt * 16 + lq;
        *(u16*)((char*)P + prow * 128 + ((pcol * 2) ^ ((prow & 7) << 4))) = f2bf(p);
      }
    }
#pragma unroll
    for (int r = 0; r < 4; ++r) {
#pragma unroll
      for (int w = 1; w < 16; w <<= 1) rsum[r] += __shfl_xor(rsum[r], w);
      lreg[r] = lreg[r] * alpha[r] + rsum[r];
    }
#pragma unroll
    for (int dt = 0; dt < 8; ++dt)
#pragma unroll
      for (int r = 0; r < 4; ++r) o[dt][r] *= alpha[r];
    // PV
#pragma unroll
    for (int kk = 0; kk < 2; ++kk) {
      short8 pa = *(const short8*)((const char*)P + lq * 128 +
                                   ((kk * 64 + lk * 16) ^ ((lq & 7) << 4)));
#pragma unroll
      for (int dt = 0; dt < 8; ++dt) {
        int dr = dt * 16 + lq;
        short8 vf = *(const short8*)((const char*)lsV + dr * 128 +
                                     ((kk * 64 + lk * 16) ^ ((dr & 7) << 4)));
        o[dt] = mfma16(pa, vf, o[dt]);
      }
    }
  }
  // epilogue
#pragma unroll
  for (int r = 0; r < 4; ++r) {
    float inv = 1.f / lreg[r];
    int row = qw + lk * 4 + r;
    u16* op = attnout + (size_t)row * 2048 + h * 128 + lq;
#pragma unroll
    for (int dt = 0; dt < 8; ++dt) op[dt * 16] = f2bf(o[dt][r] * inv);
  }
}

extern "C" void kernel_launch(void* const* d_in, const int* in_sizes, int n_in,
                              void* d_out, int out_size, void* d_ws, size_t ws_size,
                              hipStream_t stream) {
  (void)in_sizes; (void)n_in; (void)out_size; (void)ws_size;
  const float* x    = (const float*)d_in[0];
  const float* ln1g = (const float*)d_in[1];
  const float* ln1b = (const float*)d_in[2];
  const float* Wq   = (const float*)d_in[3];
  const float* Wk   = (const float*)d_in[4];
  const float* Wv   = (const float*)d_in[5];
  const float* Wp   = (const float*)d_in[6];
  const float* bp   = (const float*)d_in[7];
  const float* ln2g = (const float*)d_in[8];
  const float* ln2b = (const float*)d_in[9];
  const float* W1   = (const float*)d_in[10];
  const float* b1   = (const float*)d_in[11];
  const float* W2   = (const float*)d_in[12];
  const float* b2   = (const float*)d_in[13];
  float* out = (float*)d_out;
  char* ws = (char*)d_ws;

  u16* wqkvT = (u16*)(ws + 0);          // [6144][2048] bf16  (24 MB)
  u16* hbuf  = (u16*)(ws + 25165824);   // [2048][2048] bf16  (8 MB)
  u16* wpT   = (u16*)(ws + 33554432);   // [2048][2048] bf16  (8 MB)
  u16* w1T   = (u16*)(ws + 41943040);   // [8192][2048] bf16  (32 MB)
  u16* w2T   = (u16*)(ws + 75497472);   // [2048][8192] bf16  (32 MB)
  u16* qkv   = (u16*)(ws + 109051904);  // [2048][6144] bf16  (24 MB)
  u16* vT    = (u16*)(ws + 134217728);  // [16][128][2048] bf16 (8 MB)
  u16* attn  = (u16*)(ws + 142606336);  // [2048][2048] bf16  (8 MB)
  float* x1  = (float*)(ws + 150994944);// [2048][2048] f32   (16 MB)
  u16* g     = (u16*)(ws + 167772160);  // [2048][2048] bf16  (8 MB)
  u16* ff1   = (u16*)(ws + 0);          // [2048][8192] bf16, aliases wqkvT+hbuf (dead)
  // proj split-K partials: 2 x 16 MB over dead qkv+vT region
  float* projP = (float*)(ws + 109051904);
  // FF2 split-K partials: 2 x 16 MB over dead wpT+w1T region
  float* ffP = (float*)(ws + 33554432);

  dim3 b256(256), b512(512);
  transpose_cast<<<dim3(32, 32), b256, 0, stream>>>(Wq, wqkvT, 2048, 2048);
  transpose_cast<<<dim3(32, 32), b256, 0, stream>>>(Wk, wqkvT + 2048 * 2048, 2048, 2048);
  transpose_cast<<<dim3(32, 32), b256, 0, stream>>>(Wv, wqkvT + 4096 * 2048, 2048, 2048);
  transpose_cast<<<dim3(32, 32), b256, 0, stream>>>(Wp, wpT, 2048, 2048);
  transpose_cast<<<dim3(128, 32), b256, 0, stream>>>(W1, w1T, 2048, 8192);
  transpose_cast<<<dim3(32, 128), b256, 0, stream>>>(W2, w2T, 8192, 2048);
  ln_kernel<<<2048, b256, 0, stream>>>(x, ln1g, ln1b, hbuf);
  // QKV: [2048,2048] @ [2048,6144] -> bf16
  gemm2<0><<<dim3(48, 8, 1), b512, 0, stream>>>(hbuf, wqkvT, 2048, 6144, 2048, 2048,
                                                qkv, nullptr, nullptr);
  transpose_v<<<dim3(32, 2, 16), b256, 0, stream>>>(qkv, vT);
  attn_kernel<<<dim3(32, 16), b256, 0, stream>>>(qkv, vT, attn);
  // attn out proj, split-K=2: partials then fused reduce (+bp +x) -> x1
  gemm2<4><<<dim3(16, 8, 2), b512, 0, stream>>>(attn, wpT, 2048, 2048, 2048, 1024,
                                                nullptr, nullptr, projP);
  reduce_kernel<0><<<4096, b256, 0, stream>>>(projP, bp, x, nullptr, x1, 4194304, 2048);
  ln_kernel<<<2048, b256, 0, stream>>>(x1, ln2g, ln2b, g);
  // FF1: gelu(g @ W1 + b1) -> bf16
  gemm2<2><<<dim3(64, 8, 1), b512, 0, stream>>>(g, w1T, 2048, 8192, 2048, 2048,
                                                ff1, b1, nullptr);
  // FF2: split-K=2 (K=8192 -> 2x4096), partials then fused reduce (+b2 +x1 +g)
  gemm2<4><<<dim3(16, 8, 2), b512, 0, stream>>>(ff1, w2T, 2048, 2048, 8192, 4096,
                                                nullptr, nullptr, ffP);
  reduce_kernel<1><<<4096, b256, 0, stream>>>(ffP, b2, x1, g, out, 4194304, 2048);
}

// Round 4
// 434.791 us; speedup vs baseline: 1.2038x; 1.0227x over previous
//
#include <hip/hip_runtime.h>
#include <math.h>

typedef unsigned int u32;
typedef unsigned short u16;
typedef __attribute__((ext_vector_type(8))) short short8;
typedef __attribute__((ext_vector_type(4))) float f32x4;

__device__ __forceinline__ u16 f2bf(float f) {
  u32 u = __builtin_bit_cast(u32, f);
  u += 0x7FFFu + ((u >> 16) & 1u);
  return (u16)(u >> 16);
}
__device__ __forceinline__ float bf2f(u16 h) {
  u32 u = ((u32)h) << 16;
  return __builtin_bit_cast(float, u);
}
__device__ __forceinline__ void gload_lds16(const void* g, void* l) {
  __builtin_amdgcn_global_load_lds((const __attribute__((address_space(1))) u32*)g,
                                   (__attribute__((address_space(3))) u32*)l, 16, 0, 0);
}
__device__ __forceinline__ f32x4 mfma16(short8 a, short8 b, f32x4 c) {
  return __builtin_amdgcn_mfma_f32_16x16x32_bf16(a, b, c, 0, 0, 0);
}

// ---------------- transpose+cast: src fp32 [K][N] -> dst bf16 [N][K] ----------------
__global__ __launch_bounds__(256) void transpose_cast(const float* __restrict__ src,
                                                      u16* __restrict__ dst, int K, int N) {
  __shared__ __attribute__((aligned(16))) u16 tile[64][72];
  const int n0 = blockIdx.x * 64, k0 = blockIdx.y * 64;
  const int t = threadIdx.x;
  const int tr = t >> 4;          // 0..15
  const int tc4 = (t & 15) * 4;   // 0..60
#pragma unroll
  for (int p = 0; p < 4; ++p) {
    int row = p * 16 + tr;  // k-local
    const float4 v = *(const float4*)(src + (size_t)(k0 + row) * N + n0 + tc4);
    tile[tc4 + 0][row] = f2bf(v.x);
    tile[tc4 + 1][row] = f2bf(v.y);
    tile[tc4 + 2][row] = f2bf(v.z);
    tile[tc4 + 3][row] = f2bf(v.w);
  }
  __syncthreads();
  const int nr = t >> 2;          // 0..63
  const int kc = (t & 3) * 16;    // 0,16,32,48
  u16* d = dst + (size_t)(n0 + nr) * K + k0 + kc;
  *(short8*)(d) = *(const short8*)&tile[nr][kc];
  *(short8*)(d + 8) = *(const short8*)&tile[nr][kc + 8];
}

// ---------------- transpose V out of qkv: -> vT[h][d][kv] ----------------
__global__ __launch_bounds__(256) void transpose_v(const u16* __restrict__ qkv,
                                                   u16* __restrict__ vT) {
  __shared__ __attribute__((aligned(16))) u16 tile[64][72];
  const int kv0 = blockIdx.x * 64, d0 = blockIdx.y * 64, h = blockIdx.z;
  const int t = threadIdx.x;
  const int tr = t >> 3;         // 0..31
  const int tc8 = (t & 7) * 8;
#pragma unroll
  for (int p = 0; p < 2; ++p) {
    int row = p * 32 + tr;  // kv-local
    short8 v = *(const short8*)(qkv + (size_t)(kv0 + row) * 6144 + 4096 + h * 128 + d0 + tc8);
#pragma unroll
    for (int j = 0; j < 8; ++j) tile[tc8 + j][row] = (u16)v[j];
  }
  __syncthreads();
  const int dr = t >> 2;          // 0..63
  const int kc = (t & 3) * 16;
  u16* dst = vT + ((size_t)h * 128 + d0 + dr) * 2048 + kv0 + kc;
  *(short8*)dst = *(const short8*)&tile[dr][kc];
  *(short8*)(dst + 8) = *(const short8*)&tile[dr][kc + 8];
}

// ---------------- LayerNorm: fp32 [2048 rows][2048] -> bf16 ----------------
__global__ __launch_bounds__(256) void ln_kernel(const float* __restrict__ x,
                                                 const float* __restrict__ gw,
                                                 const float* __restrict__ bw,
                                                 u16* __restrict__ out) {
  const int row = blockIdx.x, t = threadIdx.x;
  const float* xr = x + (size_t)row * 2048;
  const float4 v0 = *(const float4*)(xr + t * 8);
  const float4 v1 = *(const float4*)(xr + t * 8 + 4);
  float s = v0.x + v0.y + v0.z + v0.w + v1.x + v1.y + v1.z + v1.w;
  float q = v0.x * v0.x + v0.y * v0.y + v0.z * v0.z + v0.w * v0.w +
            v1.x * v1.x + v1.y * v1.y + v1.z * v1.z + v1.w * v1.w;
#pragma unroll
  for (int w = 32; w; w >>= 1) { s += __shfl_xor(s, w); q += __shfl_xor(q, w); }
  __shared__ float rs[4], rq[4];
  const int wid = t >> 6, lane = t & 63;
  if (!lane) { rs[wid] = s; rq[wid] = q; }
  __syncthreads();
  s = rs[0] + rs[1] + rs[2] + rs[3];
  q = rq[0] + rq[1] + rq[2] + rq[3];
  const float mu = s * (1.f / 2048.f);
  const float var = q * (1.f / 2048.f) - mu * mu;
  const float rstd = rsqrtf(var + 1e-5f);
  const float4 g0 = *(const float4*)(gw + t * 8);
  const float4 g1 = *(const float4*)(gw + t * 8 + 4);
  const float4 b0 = *(const float4*)(bw + t * 8);
  const float4 b1 = *(const float4*)(bw + t * 8 + 4);
  short8 o;
  o[0] = (short)f2bf((v0.x - mu) * rstd * g0.x + b0.x);
  o[1] = (short)f2bf((v0.y - mu) * rstd * g0.y + b0.y);
  o[2] = (short)f2bf((v0.z - mu) * rstd * g0.z + b0.z);
  o[3] = (short)f2bf((v0.w - mu) * rstd * g0.w + b0.w);
  o[4] = (short)f2bf((v1.x - mu) * rstd * g1.x + b1.x);
  o[5] = (short)f2bf((v1.y - mu) * rstd * g1.y + b1.y);
  o[6] = (short)f2bf((v1.z - mu) * rstd * g1.z + b1.z);
  o[7] = (short)f2bf((v1.w - mu) * rstd * g1.w + b1.w);
  *(short8*)(out + (size_t)row * 2048 + t * 8) = o;
}

// ---------------- GEMM v2: 256x128 tile, BK=64, 8 waves, triple-buffer counted-vmcnt ----
template <int EPI>
__global__ __launch_bounds__(512, 2) void gemm2(const u16* __restrict__ A,
                                                const u16* __restrict__ Bt,
                                                int M, int N, int K, int Kc,
                                                u16* __restrict__ outB,
                                                const float* __restrict__ bias,
                                                float* __restrict__ pA) {
  __shared__ __attribute__((aligned(16))) u16 lds[3 * 24576];
  const int m0 = blockIdx.y * 256, n0 = blockIdx.x * 128;
  const int tid = threadIdx.x, wid = tid >> 6, lane = tid & 63;
  const int wr = wid >> 1, wc = wid & 1;       // wave grid 4M x 2N
  const int lq = lane & 15, lk = lane >> 4;
  const int kStart = blockIdx.z * Kc;
  const int NT = Kc / 64;

  size_t aoff[4], boff[2];
#pragma unroll
  for (int s = 0; s < 4; ++s) {
    int c = s * 512 + tid;
    int row = c >> 3, col = ((c & 7) ^ (row & 7)) * 8;
    aoff[s] = (size_t)(m0 + row) * K + col;
  }
#pragma unroll
  for (int s = 0; s < 2; ++s) {
    int c = s * 512 + tid;
    int row = c >> 3, col = ((c & 7) ^ (row & 7)) * 8;
    boff[s] = (size_t)(n0 + row) * K + col;
  }
  const int dstc = wid * 512 + lane * 8;

#define STAGE_A(s, t2) \
  gload_lds16(A + aoff[s] + (size_t)(kStart + (t2) * 64), \
              lds + ((t2) % 3) * 24576 + (s) * 4096 + dstc)
#define STAGE_B(s, t2) \
  gload_lds16(Bt + boff[s] + (size_t)(kStart + (t2) * 64), \
              lds + ((t2) % 3) * 24576 + 16384 + (s) * 4096 + dstc)

  STAGE_A(0, 0); STAGE_A(1, 0); STAGE_A(2, 0); STAGE_A(3, 0); STAGE_B(0, 0); STAGE_B(1, 0);
  STAGE_A(0, 1); STAGE_A(1, 1); STAGE_A(2, 1); STAGE_A(3, 1); STAGE_B(0, 1); STAGE_B(1, 1);
  asm volatile("s_waitcnt vmcnt(6)" ::: "memory");
  __builtin_amdgcn_s_barrier();
  __builtin_amdgcn_sched_barrier(0);

  f32x4 acc[4][4] = {};
  int cur = 0;
  for (int t = 0; t < NT; ++t) {
    const char* bufA = (const char*)lds + cur * 49152;
    const char* bufB = bufA + 32768;
    const int t2 = t + 2;
    const bool st = t2 < NT;
    const int xorq = (lq & 7) << 4;
#pragma unroll
    for (int ph = 0; ph < 2; ++ph) {
      short8 af[4], bf[4];
#pragma unroll
      for (int mi = 0; mi < 4; ++mi) {
        int ar = wr * 64 + mi * 16 + lq;
        af[mi] = *(const short8*)(bufA + ar * 128 + ((ph * 64 + lk * 16) ^ xorq));
      }
#pragma unroll
      for (int ni = 0; ni < 4; ++ni) {
        int br = wc * 64 + ni * 16 + lq;
        bf[ni] = *(const short8*)(bufB + br * 128 + ((ph * 64 + lk * 16) ^ xorq));
      }
      if (st) {
        if (ph == 0) { STAGE_A(0, t2); STAGE_A(1, t2); STAGE_A(2, t2); }
        else         { STAGE_A(3, t2); STAGE_B(0, t2); STAGE_B(1, t2); }
      }
      __builtin_amdgcn_s_barrier();
      __builtin_amdgcn_s_setprio(1);
#pragma unroll
      for (int mi = 0; mi < 4; ++mi)
#pragma unroll
        for (int ni = 0; ni < 4; ++ni)
          acc[mi][ni] = mfma16(af[mi], bf[ni], acc[mi][ni]);
      __builtin_amdgcn_s_setprio(0);
      if (ph == 1) {
        if (st) asm volatile("s_waitcnt vmcnt(6)" ::: "memory");
        else    asm volatile("s_waitcnt vmcnt(0)" ::: "memory");
      }
      __builtin_amdgcn_s_barrier();
      __builtin_amdgcn_sched_barrier(0);
    }
    cur = (cur == 2) ? 0 : cur + 1;
  }
#undef STAGE_A
#undef STAGE_B

  float* pp = nullptr;
  if (EPI == 4) pp = pA + (size_t)blockIdx.z * ((size_t)M * N);
#pragma unroll
  for (int mi = 0; mi < 4; ++mi) {
#pragma unroll
    for (int ni = 0; ni < 4; ++ni) {
      const int col = n0 + wc * 64 + ni * 16 + lq;
#pragma unroll
      for (int r = 0; r < 4; ++r) {
        const int row = m0 + wr * 64 + mi * 16 + lk * 4 + r;
        const size_t idx = (size_t)row * N + col;
        float v = acc[mi][ni][r];
        if (EPI == 0) {
          outB[idx] = f2bf(v);
        } else if (EPI == 2) {
          float xg = v + bias[col];
          outB[idx] = f2bf(0.5f * xg * (1.f + erff(xg * 0.70710678118654752f)));
        } else {
          pp[idx] = v;
        }
      }
    }
  }
}

// ---------------- split-K reduce: out = pA[0]+pA[1] + bias + res1 (+ bf(res2)) ----------
template <int RES2>
__global__ __launch_bounds__(256) void reduce_kernel(const float* __restrict__ pA,
                                                     const float* __restrict__ bias,
                                                     const float* __restrict__ res1,
                                                     const u16* __restrict__ res2,
                                                     float* __restrict__ out,
                                                     int MN, int N) {
  const int i = (blockIdx.x * 256 + threadIdx.x) * 4;
  if (i >= MN) return;
  float4 s = *(const float4*)(pA + i);
  {
    const float4 t = *(const float4*)(pA + MN + i);
    s.x += t.x; s.y += t.y; s.z += t.z; s.w += t.w;
  }
  const int col = i & (N - 1);
  const float4 bv = *(const float4*)(bias + col);
  const float4 r1 = *(const float4*)(res1 + i);
  float4 o;
  o.x = s.x + bv.x + r1.x;
  o.y = s.y + bv.y + r1.y;
  o.z = s.z + bv.z + r1.z;
  o.w = s.w + bv.w + r1.w;
  if (RES2) {
    const u16* r2 = res2 + i;
    o.x += bf2f(r2[0]); o.y += bf2f(r2[1]); o.z += bf2f(r2[2]); o.w += bf2f(r2[3]);
  }
  *(float4*)(out + i) = o;
}

// ---------------- flash attention (causal), 4 waves x 16 q-rows, KVBLK=64 ----------------
// grid (head=16, qslot=32); qi = 31 - qslot so heaviest q-tiles dispatch FIRST
// (LPT load balance: block qi does qi+1 KV-tiles). T13 defer-max: skip O-rescale
// when tile max doesn't grow past mreg+8 (wave-uniform ballot).
__global__ __launch_bounds__(256) void attn_kernel(const u16* __restrict__ qkv,
                                                   const u16* __restrict__ vT,
                                                   u16* __restrict__ attnout) {
  __shared__ __attribute__((aligned(16))) u16 lsK[64 * 128];   // [kv][d], swizzled
  __shared__ __attribute__((aligned(16))) u16 lsV[128 * 64];   // [d][kv], swizzled
  __shared__ __attribute__((aligned(16))) u16 lsP[4][16 * 64]; // per-wave P, swizzled
  const int h = blockIdx.x;
  const int qi = 31 - blockIdx.y;   // heavy-first dispatch
  const int qb = qi * 64;
  const int tid = threadIdx.x, wid = tid >> 6, lane = tid & 63;
  const int lq = lane & 15, lk = lane >> 4;
  const int qw = qb + wid * 16;

  short8 qf[4];
  {
    const u16* qp = qkv + (size_t)(qw + lq) * 6144 + h * 128;
#pragma unroll
    for (int ks = 0; ks < 4; ++ks) qf[ks] = *(const short8*)(qp + ks * 32 + lk * 8);
  }
  float mreg[4], lreg[4];
  f32x4 o[8];
#pragma unroll
  for (int r = 0; r < 4; ++r) { mreg[r] = -INFINITY; lreg[r] = 0.f; }
#pragma unroll
  for (int dt = 0; dt < 8; ++dt) o[dt] = (f32x4){0.f, 0.f, 0.f, 0.f};

  const int rK = lane >> 4, sK = lane & 15;
  const int rV = lane >> 3, sV = lane & 7;
  const int nkt = qi + 1;
  for (int kt = 0; kt < nkt; ++kt) {
    const int kv0 = kt * 64;
    if (kt) __syncthreads();
#pragma unroll
    for (int i = 0; i < 4; ++i) {
      int c = wid * 4 + i;
      int rowK = c * 4 + rK;
      gload_lds16(qkv + (size_t)(kv0 + rowK) * 6144 + 2048 + h * 128 + ((sK ^ (rowK & 7)) * 8),
                  lsK + c * 512);
      int rowV = c * 8 + rV;
      gload_lds16(vT + ((size_t)h * 128 + rowV) * 2048 + kv0 + ((sV ^ (rowV & 7)) * 8),
                  lsV + c * 512);
    }
    __syncthreads();

    // QK^T (S tile 16x64)
    f32x4 sc[4];
#pragma unroll
    for (int nt = 0; nt < 4; ++nt) sc[nt] = (f32x4){0.f, 0.f, 0.f, 0.f};
#pragma unroll
    for (int ks = 0; ks < 4; ++ks) {
#pragma unroll
      for (int nt = 0; nt < 4; ++nt) {
        int kvr = nt * 16 + lq;
        short8 kf = *(const short8*)((const char*)lsK + kvr * 256 +
                                     ((ks * 64 + lk * 16) ^ ((kvr & 7) << 4)));
        sc[nt] = mfma16(qf[ks], kf, sc[nt]);
      }
    }
    // scale + causal mask + row max
    float rmax[4] = {-INFINITY, -INFINITY, -INFINITY, -INFINITY};
#pragma unroll
    for (int nt = 0; nt < 4; ++nt) {
      int kv = kv0 + nt * 16 + lq;
#pragma unroll
      for (int r = 0; r < 4; ++r) {
        int qrow = qw + lk * 4 + r;
        float s = (kv <= qrow) ? sc[nt][r] * 0.08838834764831845f : -INFINITY;
        sc[nt][r] = s;
        rmax[r] = fmaxf(rmax[r], s);
      }
    }
#pragma unroll
    for (int r = 0; r < 4; ++r)
#pragma unroll
      for (int w = 1; w < 16; w <<= 1) rmax[r] = fmaxf(rmax[r], __shfl_xor(rmax[r], w));
    // T13 defer-max: rescale only if some row's max grew past mreg+8
    bool grow = false;
#pragma unroll
    for (int r = 0; r < 4; ++r) grow |= (rmax[r] > mreg[r] + 8.f);
    if (__any(grow)) {
#pragma unroll
      for (int r = 0; r < 4; ++r) {
        float mn = fmaxf(mreg[r], rmax[r]);
        float alpha = __expf(mreg[r] - mn);
        mreg[r] = mn;
        lreg[r] *= alpha;
#pragma unroll
        for (int dt = 0; dt < 8; ++dt) o[dt][r] *= alpha;
      }
    }
    float rsum[4] = {0.f, 0.f, 0.f, 0.f};
    u16* P = &lsP[wid][0];
#pragma unroll
    for (int nt = 0; nt < 4; ++nt) {
#pragma unroll
      for (int r = 0; r < 4; ++r) {
        float p = __expf(sc[nt][r] - mreg[r]);
        rsum[r] += p;
        int prow = lk * 4 + r, pcol = nt * 16 + lq;
        *(u16*)((char*)P + prow * 128 + ((pcol * 2) ^ ((prow & 7) << 4))) = f2bf(p);
      }
    }
#pragma unroll
    for (int r = 0; r < 4; ++r) {
#pragma unroll
      for (int w = 1; w < 16; w <<= 1) rsum[r] += __shfl_xor(rsum[r], w);
      lreg[r] += rsum[r];
    }
    // PV
#pragma unroll
    for (int kk = 0; kk < 2; ++kk) {
      short8 pa = *(const short8*)((const char*)P + lq * 128 +
                                   ((kk * 64 + lk * 16) ^ ((lq & 7) << 4)));
#pragma unroll
      for (int dt = 0; dt < 8; ++dt) {
        int dr = dt * 16 + lq;
        short8 vf = *(const short8*)((const char*)lsV + dr * 128 +
                                     ((kk * 64 + lk * 16) ^ ((dr & 7) << 4)));
        o[dt] = mfma16(pa, vf, o[dt]);
      }
    }
  }
  // epilogue
#pragma unroll
  for (int r = 0; r < 4; ++r) {
    float inv = 1.f / lreg[r];
    int row = qw + lk * 4 + r;
    u16* op = attnout + (size_t)row * 2048 + h * 128 + lq;
#pragma unroll
    for (int dt = 0; dt < 8; ++dt) op[dt * 16] = f2bf(o[dt][r] * inv);
  }
}

extern "C" void kernel_launch(void* const* d_in, const int* in_sizes, int n_in,
                              void* d_out, int out_size, void* d_ws, size_t ws_size,
                              hipStream_t stream) {
  (void)in_sizes; (void)n_in; (void)out_size; (void)ws_size;
  const float* x    = (const float*)d_in[0];
  const float* ln1g = (const float*)d_in[1];
  const float* ln1b = (const float*)d_in[2];
  const float* Wq   = (const float*)d_in[3];
  const float* Wk   = (const float*)d_in[4];
  const float* Wv   = (const float*)d_in[5];
  const float* Wp   = (const float*)d_in[6];
  const float* bp   = (const float*)d_in[7];
  const float* ln2g = (const float*)d_in[8];
  const float* ln2b = (const float*)d_in[9];
  const float* W1   = (const float*)d_in[10];
  const float* b1   = (const float*)d_in[11];
  const float* W2   = (const float*)d_in[12];
  const float* b2   = (const float*)d_in[13];
  float* out = (float*)d_out;
  char* ws = (char*)d_ws;

  u16* wqkvT = (u16*)(ws + 0);          // [6144][2048] bf16  (24 MB)
  u16* hbuf  = (u16*)(ws + 25165824);   // [2048][2048] bf16  (8 MB)
  u16* wpT   = (u16*)(ws + 33554432);   // [2048][2048] bf16  (8 MB)
  u16* w1T   = (u16*)(ws + 41943040);   // [8192][2048] bf16  (32 MB)
  u16* w2T   = (u16*)(ws + 75497472);   // [2048][8192] bf16  (32 MB)
  u16* qkv   = (u16*)(ws + 109051904);  // [2048][6144] bf16  (24 MB)
  u16* vT    = (u16*)(ws + 134217728);  // [16][128][2048] bf16 (8 MB)
  u16* attn  = (u16*)(ws + 142606336);  // [2048][2048] bf16  (8 MB)
  float* x1  = (float*)(ws + 150994944);// [2048][2048] f32   (16 MB)
  u16* g     = (u16*)(ws + 167772160);  // [2048][2048] bf16  (8 MB)
  u16* ff1   = (u16*)(ws + 0);          // [2048][8192] bf16, aliases wqkvT+hbuf (dead)
  float* projP = (float*)(ws + 109051904); // 2 x 16 MB over dead qkv+vT
  float* ffP = (float*)(ws + 33554432);    // 2 x 16 MB over dead wpT+w1T

  dim3 b256(256), b512(512);
  transpose_cast<<<dim3(32, 32), b256, 0, stream>>>(Wq, wqkvT, 2048, 2048);
  transpose_cast<<<dim3(32, 32), b256, 0, stream>>>(Wk, wqkvT + 2048 * 2048, 2048, 2048);
  transpose_cast<<<dim3(32, 32), b256, 0, stream>>>(Wv, wqkvT + 4096 * 2048, 2048, 2048);
  transpose_cast<<<dim3(32, 32), b256, 0, stream>>>(Wp, wpT, 2048, 2048);
  transpose_cast<<<dim3(128, 32), b256, 0, stream>>>(W1, w1T, 2048, 8192);
  transpose_cast<<<dim3(32, 128), b256, 0, stream>>>(W2, w2T, 8192, 2048);
  ln_kernel<<<2048, b256, 0, stream>>>(x, ln1g, ln1b, hbuf);
  gemm2<0><<<dim3(48, 8, 1), b512, 0, stream>>>(hbuf, wqkvT, 2048, 6144, 2048, 2048,
                                                qkv, nullptr, nullptr);
  transpose_v<<<dim3(32, 2, 16), b256, 0, stream>>>(qkv, vT);
  attn_kernel<<<dim3(16, 32), b256, 0, stream>>>(qkv, vT, attn);
  gemm2<4><<<dim3(16, 8, 2), b512, 0, stream>>>(attn, wpT, 2048, 2048, 2048, 1024,
                                                nullptr, nullptr, projP);
  reduce_kernel<0><<<4096, b256, 0, stream>>>(projP, bp, x, nullptr, x1, 4194304, 2048);
  ln_kernel<<<2048, b256, 0, stream>>>(x1, ln2g, ln2b, g);
  gemm2<2><<<dim3(64, 8, 1), b512, 0, stream>>>(g, w1T, 2048, 8192, 2048, 2048,
                                                ff1, b1, nullptr);
  gemm2<4><<<dim3(16, 8, 2), b512, 0, stream>>>(ff1, w2T, 2048, 2048, 8192, 4096,
                                                nullptr, nullptr, ffP);
  reduce_kernel<1><<<4096, b256, 0, stream>>>(ffP, b2, x1, g, out, 4194304, 2048);
}

// Round 5
// 423.831 us; speedup vs baseline: 1.2349x; 1.0259x over previous
//
#include <hip/hip_runtime.h>
#include <math.h>

typedef unsigned int u32;
typedef unsigned short u16;
typedef __attribute__((ext_vector_type(8))) short short8;
typedef __attribute__((ext_vector_type(4))) float f32x4;

__device__ __forceinline__ u16 f2bf(float f) {
  u32 u = __builtin_bit_cast(u32, f);
  u += 0x7FFFu + ((u >> 16) & 1u);
  return (u16)(u >> 16);
}
__device__ __forceinline__ float bf2f(u16 h) {
  u32 u = ((u32)h) << 16;
  return __builtin_bit_cast(float, u);
}
__device__ __forceinline__ void gload_lds16(const void* g, void* l) {
  __builtin_amdgcn_global_load_lds((const __attribute__((address_space(1))) u32*)g,
                                   (__attribute__((address_space(3))) u32*)l, 16, 0, 0);
}
__device__ __forceinline__ f32x4 mfma16(short8 a, short8 b, f32x4 c) {
  return __builtin_amdgcn_mfma_f32_16x16x32_bf16(a, b, c, 0, 0, 0);
}

// ---------------- transpose+cast: src fp32 [K][N] -> dst bf16 [N][K] ----------------
__global__ __launch_bounds__(256) void transpose_cast(const float* __restrict__ src,
                                                      u16* __restrict__ dst, int K, int N) {
  __shared__ __attribute__((aligned(16))) u16 tile[64][72];
  const int n0 = blockIdx.x * 64, k0 = blockIdx.y * 64;
  const int t = threadIdx.x;
  const int tr = t >> 4;          // 0..15
  const int tc4 = (t & 15) * 4;   // 0..60
#pragma unroll
  for (int p = 0; p < 4; ++p) {
    int row = p * 16 + tr;  // k-local
    const float4 v = *(const float4*)(src + (size_t)(k0 + row) * N + n0 + tc4);
    tile[tc4 + 0][row] = f2bf(v.x);
    tile[tc4 + 1][row] = f2bf(v.y);
    tile[tc4 + 2][row] = f2bf(v.z);
    tile[tc4 + 3][row] = f2bf(v.w);
  }
  __syncthreads();
  const int nr = t >> 2;          // 0..63
  const int kc = (t & 3) * 16;    // 0,16,32,48
  u16* d = dst + (size_t)(n0 + nr) * K + k0 + kc;
  *(short8*)(d) = *(const short8*)&tile[nr][kc];
  *(short8*)(d + 8) = *(const short8*)&tile[nr][kc + 8];
}

// ---------------- transpose V out of qkv: -> vT[h][d][kv] ----------------
__global__ __launch_bounds__(256) void transpose_v(const u16* __restrict__ qkv,
                                                   u16* __restrict__ vT) {
  __shared__ __attribute__((aligned(16))) u16 tile[64][72];
  const int kv0 = blockIdx.x * 64, d0 = blockIdx.y * 64, h = blockIdx.z;
  const int t = threadIdx.x;
  const int tr = t >> 3;         // 0..31
  const int tc8 = (t & 7) * 8;
#pragma unroll
  for (int p = 0; p < 2; ++p) {
    int row = p * 32 + tr;  // kv-local
    short8 v = *(const short8*)(qkv + (size_t)(kv0 + row) * 6144 + 4096 + h * 128 + d0 + tc8);
#pragma unroll
    for (int j = 0; j < 8; ++j) tile[tc8 + j][row] = (u16)v[j];
  }
  __syncthreads();
  const int dr = t >> 2;          // 0..63
  const int kc = (t & 3) * 16;
  u16* dst = vT + ((size_t)h * 128 + d0 + dr) * 2048 + kv0 + kc;
  *(short8*)dst = *(const short8*)&tile[dr][kc];
  *(short8*)(dst + 8) = *(const short8*)&tile[dr][kc + 8];
}

// ---------------- LayerNorm: fp32 [2048 rows][2048] -> bf16 ----------------
__global__ __launch_bounds__(256) void ln_kernel(const float* __restrict__ x,
                                                 const float* __restrict__ gw,
                                                 const float* __restrict__ bw,
                                                 u16* __restrict__ out) {
  const int row = blockIdx.x, t = threadIdx.x;
  const float* xr = x + (size_t)row * 2048;
  const float4 v0 = *(const float4*)(xr + t * 8);
  const float4 v1 = *(const float4*)(xr + t * 8 + 4);
  float s = v0.x + v0.y + v0.z + v0.w + v1.x + v1.y + v1.z + v1.w;
  float q = v0.x * v0.x + v0.y * v0.y + v0.z * v0.z + v0.w * v0.w +
            v1.x * v1.x + v1.y * v1.y + v1.z * v1.z + v1.w * v1.w;
#pragma unroll
  for (int w = 32; w; w >>= 1) { s += __shfl_xor(s, w); q += __shfl_xor(q, w); }
  __shared__ float rs[4], rq[4];
  const int wid = t >> 6, lane = t & 63;
  if (!lane) { rs[wid] = s; rq[wid] = q; }
  __syncthreads();
  s = rs[0] + rs[1] + rs[2] + rs[3];
  q = rq[0] + rq[1] + rq[2] + rq[3];
  const float mu = s * (1.f / 2048.f);
  const float var = q * (1.f / 2048.f) - mu * mu;
  const float rstd = rsqrtf(var + 1e-5f);
  const float4 g0 = *(const float4*)(gw + t * 8);
  const float4 g1 = *(const float4*)(gw + t * 8 + 4);
  const float4 b0 = *(const float4*)(bw + t * 8);
  const float4 b1 = *(const float4*)(bw + t * 8 + 4);
  short8 o;
  o[0] = (short)f2bf((v0.x - mu) * rstd * g0.x + b0.x);
  o[1] = (short)f2bf((v0.y - mu) * rstd * g0.y + b0.y);
  o[2] = (short)f2bf((v0.z - mu) * rstd * g0.z + b0.z);
  o[3] = (short)f2bf((v0.w - mu) * rstd * g0.w + b0.w);
  o[4] = (short)f2bf((v1.x - mu) * rstd * g1.x + b1.x);
  o[5] = (short)f2bf((v1.y - mu) * rstd * g1.y + b1.y);
  o[6] = (short)f2bf((v1.z - mu) * rstd * g1.z + b1.z);
  o[7] = (short)f2bf((v1.w - mu) * rstd * g1.w + b1.w);
  *(short8*)(out + (size_t)row * 2048 + t * 8) = o;
}

// ---------------- GEMM v3: 256x256 tile, BK=32, 8 waves (2Mx4N), triple-buffer ----------
// Per-wave output 128x64 (8m x 4n frags). B-frags held in regs across the K-tile.
// Stage K-tile t+2 while computing t (staged buffer never read -> race-free);
// boundary wait = counted vmcnt(4) (iter-t's own 4 loads stay in flight).
// One barrier per K-tile. XOR swizzle: chunk = lk ^ ((row>>1)&3) on 64B rows,
// applied on BOTH the pre-swizzled global source and the LDS read (involution).
// EPI 0: out bf16 plain; EPI 2: out bf16 = gelu(v+bias); EPI 4: f32 partials
// (blockIdx.z<2 -> pA, else pB; 2 tiles each).
template <int EPI>
__global__ __launch_bounds__(512, 2) void gemm3(const u16* __restrict__ A,
                                                const u16* __restrict__ Bt,
                                                int M, int N, int K, int Kc,
                                                u16* __restrict__ outB,
                                                const float* __restrict__ bias,
                                                float* __restrict__ pA,
                                                float* __restrict__ pB) {
  // per buffer: A[256][32] (8192 u16) + B[256][32] (8192 u16) = 16384 u16 (32 KB); x3
  __shared__ __attribute__((aligned(16))) u16 lds[3 * 16384];
  const int m0 = blockIdx.y * 256, n0 = blockIdx.x * 256;
  const int tid = threadIdx.x, wid = tid >> 6, lane = tid & 63;
  const int wr = wid >> 2, wc = wid & 3;   // wave grid 2M x 4N
  const int lq = lane & 15, lk = lane >> 4;
  const int kStart = blockIdx.z * Kc;
  const int NT = Kc / 32;

  // staging geometry: 1024 chunks of 16B per tile half (A or B); chunk c:
  // row = c>>2, in-row 16B slot j = c&3; global col = (j ^ ((row>>1)&3))*8
  size_t aoff[2], boff[2];
#pragma unroll
  for (int s = 0; s < 2; ++s) {
    int c = s * 512 + tid;
    int row = c >> 2;
    int col = ((c & 3) ^ ((row >> 1) & 3)) * 8;
    aoff[s] = (size_t)(m0 + row) * K + kStart + col;
    boff[s] = (size_t)(n0 + row) * K + kStart + col;
  }
  u16* ldst = lds + tid * 8;  // wave-uniform base + lane*16B

#define STA(s, buf, t2) gload_lds16(A + aoff[s] + (size_t)((t2) * 32), \
                                    ldst + (buf) * 16384 + (s) * 4096)
#define STB(s, buf, t2) gload_lds16(Bt + boff[s] + (size_t)((t2) * 32), \
                                    ldst + (buf) * 16384 + 8192 + (s) * 4096)

  // prologue: fully stage K-tiles 0 and 1 (NT >= 3 always here)
  STA(0, 0, 0); STA(1, 0, 0); STB(0, 0, 0); STB(1, 0, 0);
  STA(0, 1, 1); STA(1, 1, 1); STB(0, 1, 1); STB(1, 1, 1);
  asm volatile("s_waitcnt vmcnt(4)" ::: "memory");  // K-tile 0 complete
  __builtin_amdgcn_s_barrier();
  __builtin_amdgcn_sched_barrier(0);

  f32x4 acc[8][4] = {};
  int cur = 0, nxt2 = 2;
  for (int t = 0; t < NT; ++t) {
    const char* bufc = (const char*)lds + cur * 32768;
    const bool st = (t + 2) < NT;
    short8 bf[4], af[4];
#pragma unroll
    for (int ni = 0; ni < 4; ++ni) {
      int br = wc * 64 + ni * 16 + lq;
      bf[ni] = *(const short8*)(bufc + 16384 + br * 64 + ((lk ^ ((br >> 1) & 3)) << 4));
    }
#pragma unroll
    for (int mi = 0; mi < 4; ++mi) {
      int ar = wr * 128 + mi * 16 + lq;
      af[mi] = *(const short8*)(bufc + ar * 64 + ((lk ^ ((ar >> 1) & 3)) << 4));
    }
    if (st) { STA(0, nxt2, t + 2); STA(1, nxt2, t + 2); }
    __builtin_amdgcn_s_setprio(1);
#pragma unroll
    for (int mi = 0; mi < 4; ++mi)
#pragma unroll
      for (int ni = 0; ni < 4; ++ni)
        acc[mi][ni] = mfma16(af[mi], bf[ni], acc[mi][ni]);
    __builtin_amdgcn_s_setprio(0);
#pragma unroll
    for (int mi = 0; mi < 4; ++mi) {
      int ar = wr * 128 + (mi + 4) * 16 + lq;
      af[mi] = *(const short8*)(bufc + ar * 64 + ((lk ^ ((ar >> 1) & 3)) << 4));
    }
    if (st) { STB(0, nxt2, t + 2); STB(1, nxt2, t + 2); }
    __builtin_amdgcn_s_setprio(1);
#pragma unroll
    for (int mi = 0; mi < 4; ++mi)
#pragma unroll
      for (int ni = 0; ni < 4; ++ni)
        acc[mi + 4][ni] = mfma16(af[mi], bf[ni], acc[mi + 4][ni]);
    __builtin_amdgcn_s_setprio(0);
    if (st) asm volatile("s_waitcnt vmcnt(4)" ::: "memory");  // t+1 done, t+2 in flight
    else    asm volatile("s_waitcnt vmcnt(0)" ::: "memory");  // tail drain
    __builtin_amdgcn_s_barrier();
    __builtin_amdgcn_sched_barrier(0);
    cur = (cur == 2) ? 0 : cur + 1;
    nxt2 = (nxt2 == 2) ? 0 : nxt2 + 1;
  }
#undef STA
#undef STB

  // epilogue
  float* pp = nullptr;
  if (EPI == 4) {
    pp = (blockIdx.z < 2 ? pA : pB) + (size_t)(blockIdx.z & 1) * ((size_t)M * N);
  }
#pragma unroll
  for (int mi = 0; mi < 8; ++mi) {
#pragma unroll
    for (int ni = 0; ni < 4; ++ni) {
      const int col = n0 + wc * 64 + ni * 16 + lq;
#pragma unroll
      for (int r = 0; r < 4; ++r) {
        const int row = m0 + wr * 128 + mi * 16 + lk * 4 + r;
        const size_t idx = (size_t)row * N + col;
        float v = acc[mi][ni][r];
        if (EPI == 0) {
          outB[idx] = f2bf(v);
        } else if (EPI == 2) {
          float xg = v + bias[col];
          outB[idx] = f2bf(0.5f * xg * (1.f + erff(xg * 0.70710678118654752f)));
        } else {
          pp[idx] = v;
        }
      }
    }
  }
}

// ---------------- split-K reduce: out = sum partials + bias + res1 (+ bf(res2)) --------
template <int NS, int RES2>
__global__ __launch_bounds__(256) void reduce_kernel(const float* __restrict__ pA,
                                                     const float* __restrict__ pB,
                                                     const float* __restrict__ bias,
                                                     const float* __restrict__ res1,
                                                     const u16* __restrict__ res2,
                                                     float* __restrict__ out,
                                                     int MN, int N) {
  const int i = (blockIdx.x * 256 + threadIdx.x) * 4;
  if (i >= MN) return;
  float4 s = *(const float4*)(pA + i);
  {
    const float4 t = *(const float4*)(pA + MN + i);
    s.x += t.x; s.y += t.y; s.z += t.z; s.w += t.w;
  }
  if (NS == 4) {
    const float4 t0 = *(const float4*)(pB + i);
    const float4 t1 = *(const float4*)(pB + MN + i);
    s.x += t0.x + t1.x; s.y += t0.y + t1.y; s.z += t0.z + t1.z; s.w += t0.w + t1.w;
  }
  const int col = i & (N - 1);
  const float4 bv = *(const float4*)(bias + col);
  const float4 r1 = *(const float4*)(res1 + i);
  float4 o;
  o.x = s.x + bv.x + r1.x;
  o.y = s.y + bv.y + r1.y;
  o.z = s.z + bv.z + r1.z;
  o.w = s.w + bv.w + r1.w;
  if (RES2) {
    const u16* r2 = res2 + i;
    o.x += bf2f(r2[0]); o.y += bf2f(r2[1]); o.z += bf2f(r2[2]); o.w += bf2f(r2[3]);
  }
  *(float4*)(out + i) = o;
}

// ---------------- flash attention (causal), 4 waves x 16 q-rows, KVBLK=64 ----------------
// grid (head=16, qslot=32); qi = 31 - qslot so heaviest q-tiles dispatch FIRST.
// T13 defer-max: skip O-rescale when tile max doesn't grow past mreg+8.
__global__ __launch_bounds__(256) void attn_kernel(const u16* __restrict__ qkv,
                                                   const u16* __restrict__ vT,
                                                   u16* __restrict__ attnout) {
  __shared__ __attribute__((aligned(16))) u16 lsK[64 * 128];   // [kv][d], swizzled
  __shared__ __attribute__((aligned(16))) u16 lsV[128 * 64];   // [d][kv], swizzled
  __shared__ __attribute__((aligned(16))) u16 lsP[4][16 * 64]; // per-wave P, swizzled
  const int h = blockIdx.x;
  const int qi = 31 - blockIdx.y;   // heavy-first dispatch
  const int qb = qi * 64;
  const int tid = threadIdx.x, wid = tid >> 6, lane = tid & 63;
  const int lq = lane & 15, lk = lane >> 4;
  const int qw = qb + wid * 16;

  short8 qf[4];
  {
    const u16* qp = qkv + (size_t)(qw + lq) * 6144 + h * 128;
#pragma unroll
    for (int ks = 0; ks < 4; ++ks) qf[ks] = *(const short8*)(qp + ks * 32 + lk * 8);
  }
  float mreg[4], lreg[4];
  f32x4 o[8];
#pragma unroll
  for (int r = 0; r < 4; ++r) { mreg[r] = -INFINITY; lreg[r] = 0.f; }
#pragma unroll
  for (int dt = 0; dt < 8; ++dt) o[dt] = (f32x4){0.f, 0.f, 0.f, 0.f};

  const int rK = lane >> 4, sK = lane & 15;
  const int rV = lane >> 3, sV = lane & 7;
  const int nkt = qi + 1;
  for (int kt = 0; kt < nkt; ++kt) {
    const int kv0 = kt * 64;
    if (kt) __syncthreads();
#pragma unroll
    for (int i = 0; i < 4; ++i) {
      int c = wid * 4 + i;
      int rowK = c * 4 + rK;
      gload_lds16(qkv + (size_t)(kv0 + rowK) * 6144 + 2048 + h * 128 + ((sK ^ (rowK & 7)) * 8),
                  lsK + c * 512);
      int rowV = c * 8 + rV;
      gload_lds16(vT + ((size_t)h * 128 + rowV) * 2048 + kv0 + ((sV ^ (rowV & 7)) * 8),
                  lsV + c * 512);
    }
    __syncthreads();

    // QK^T (S tile 16x64)
    f32x4 sc[4];
#pragma unroll
    for (int nt = 0; nt < 4; ++nt) sc[nt] = (f32x4){0.f, 0.f, 0.f, 0.f};
#pragma unroll
    for (int ks = 0; ks < 4; ++ks) {
#pragma unroll
      for (int nt = 0; nt < 4; ++nt) {
        int kvr = nt * 16 + lq;
        short8 kf = *(const short8*)((const char*)lsK + kvr * 256 +
                                     ((ks * 64 + lk * 16) ^ ((kvr & 7) << 4)));
        sc[nt] = mfma16(qf[ks], kf, sc[nt]);
      }
    }
    // scale + causal mask + row max
    float rmax[4] = {-INFINITY, -INFINITY, -INFINITY, -INFINITY};
#pragma unroll
    for (int nt = 0; nt < 4; ++nt) {
      int kv = kv0 + nt * 16 + lq;
#pragma unroll
      for (int r = 0; r < 4; ++r) {
        int qrow = qw + lk * 4 + r;
        float s = (kv <= qrow) ? sc[nt][r] * 0.08838834764831845f : -INFINITY;
        sc[nt][r] = s;
        rmax[r] = fmaxf(rmax[r], s);
      }
    }
#pragma unroll
    for (int r = 0; r < 4; ++r)
#pragma unroll
      for (int w = 1; w < 16; w <<= 1) rmax[r] = fmaxf(rmax[r], __shfl_xor(rmax[r], w));
    // T13 defer-max: rescale only if some row's max grew past mreg+8
    bool grow = false;
#pragma unroll
    for (int r = 0; r < 4; ++r) grow |= (rmax[r] > mreg[r] + 8.f);
    if (__any(grow)) {
#pragma unroll
      for (int r = 0; r < 4; ++r) {
        float mn = fmaxf(mreg[r], rmax[r]);
        float alpha = __expf(mreg[r] - mn);
        mreg[r] = mn;
        lreg[r] *= alpha;
#pragma unroll
        for (int dt = 0; dt < 8; ++dt) o[dt][r] *= alpha;
      }
    }
    float rsum[4] = {0.f, 0.f, 0.f, 0.f};
    u16* P = &lsP[wid][0];
#pragma unroll
    for (int nt = 0; nt < 4; ++nt) {
#pragma unroll
      for (int r = 0; r < 4; ++r) {
        float p = __expf(sc[nt][r] - mreg[r]);
        rsum[r] += p;
        int prow = lk * 4 + r, pcol = nt * 16 + lq;
        *(u16*)((char*)P + prow * 128 + ((pcol * 2) ^ ((prow & 7) << 4))) = f2bf(p);
      }
    }
#pragma unroll
    for (int r = 0; r < 4; ++r) {
#pragma unroll
      for (int w = 1; w < 16; w <<= 1) rsum[r] += __shfl_xor(rsum[r], w);
      lreg[r] += rsum[r];
    }
    // PV
#pragma unroll
    for (int kk = 0; kk < 2; ++kk) {
      short8 pa = *(const short8*)((const char*)P + lq * 128 +
                                   ((kk * 64 + lk * 16) ^ ((lq & 7) << 4)));
#pragma unroll
      for (int dt = 0; dt < 8; ++dt) {
        int dr = dt * 16 + lq;
        short8 vf = *(const short8*)((const char*)lsV + dr * 128 +
                                     ((kk * 64 + lk * 16) ^ ((dr & 7) << 4)));
        o[dt] = mfma16(pa, vf, o[dt]);
      }
    }
  }
  // epilogue
#pragma unroll
  for (int r = 0; r < 4; ++r) {
    float inv = 1.f / lreg[r];
    int row = qw + lk * 4 + r;
    u16* op = attnout + (size_t)row * 2048 + h * 128 + lq;
#pragma unroll
    for (int dt = 0; dt < 8; ++dt) op[dt * 16] = f2bf(o[dt][r] * inv);
  }
}

extern "C" void kernel_launch(void* const* d_in, const int* in_sizes, int n_in,
                              void* d_out, int out_size, void* d_ws, size_t ws_size,
                              hipStream_t stream) {
  (void)in_sizes; (void)n_in; (void)out_size; (void)ws_size;
  const float* x    = (const float*)d_in[0];
  const float* ln1g = (const float*)d_in[1];
  const float* ln1b = (const float*)d_in[2];
  const float* Wq   = (const float*)d_in[3];
  const float* Wk   = (const float*)d_in[4];
  const float* Wv   = (const float*)d_in[5];
  const float* Wp   = (const float*)d_in[6];
  const float* bp   = (const float*)d_in[7];
  const float* ln2g = (const float*)d_in[8];
  const float* ln2b = (const float*)d_in[9];
  const float* W1   = (const float*)d_in[10];
  const float* b1   = (const float*)d_in[11];
  const float* W2   = (const float*)d_in[12];
  const float* b2   = (const float*)d_in[13];
  float* out = (float*)d_out;
  char* ws = (char*)d_ws;

  u16* wqkvT = (u16*)(ws + 0);          // [6144][2048] bf16  (24 MB)
  u16* hbuf  = (u16*)(ws + 25165824);   // [2048][2048] bf16  (8 MB)
  u16* wpT   = (u16*)(ws + 33554432);   // [2048][2048] bf16  (8 MB)
  u16* w1T   = (u16*)(ws + 41943040);   // [8192][2048] bf16  (32 MB)
  u16* w2T   = (u16*)(ws + 75497472);   // [2048][8192] bf16  (32 MB)
  u16* qkv   = (u16*)(ws + 109051904);  // [2048][6144] bf16  (24 MB)
  u16* vT    = (u16*)(ws + 134217728);  // [16][128][2048] bf16 (8 MB)
  u16* attn  = (u16*)(ws + 142606336);  // [2048][2048] bf16  (8 MB)
  float* x1  = (float*)(ws + 150994944);// [2048][2048] f32   (16 MB)
  u16* g     = (u16*)(ws + 167772160);  // [2048][2048] bf16  (8 MB)
  u16* ff1   = (u16*)(ws + 0);          // [2048][8192] bf16, aliases wqkvT+hbuf (dead)
  // proj partials (4x16MB): [0,32M) wqkvT+hbuf dead; [104M,136M) qkv+vT dead after attn
  float* projPA = (float*)(ws + 0);
  float* projPB = (float*)(ws + 109051904);
  // FF2 partials (4x16MB): [32M,64M) wpT+w1T dead after FF1; [104M,136M) dead
  float* ffPA = (float*)(ws + 33554432);
  float* ffPB = (float*)(ws + 109051904);

  dim3 b256(256), b512(512);
  transpose_cast<<<dim3(32, 32), b256, 0, stream>>>(Wq, wqkvT, 2048, 2048);
  transpose_cast<<<dim3(32, 32), b256, 0, stream>>>(Wk, wqkvT + 2048 * 2048, 2048, 2048);
  transpose_cast<<<dim3(32, 32), b256, 0, stream>>>(Wv, wqkvT + 4096 * 2048, 2048, 2048);
  transpose_cast<<<dim3(32, 32), b256, 0, stream>>>(Wp, wpT, 2048, 2048);
  transpose_cast<<<dim3(128, 32), b256, 0, stream>>>(W1, w1T, 2048, 8192);
  transpose_cast<<<dim3(32, 128), b256, 0, stream>>>(W2, w2T, 8192, 2048);
  ln_kernel<<<2048, b256, 0, stream>>>(x, ln1g, ln1b, hbuf);
  // QKV: [2048,2048] @ [2048,6144] -> bf16
  gemm3<0><<<dim3(24, 8, 1), b512, 0, stream>>>(hbuf, wqkvT, 2048, 6144, 2048, 2048,
                                                qkv, nullptr, nullptr, nullptr);
  transpose_v<<<dim3(32, 2, 16), b256, 0, stream>>>(qkv, vT);
  attn_kernel<<<dim3(16, 32), b256, 0, stream>>>(qkv, vT, attn);
  // attn out proj, split-K=4 (Kc=512): partials then fused reduce (+bp +x) -> x1
  gemm3<4><<<dim3(8, 8, 4), b512, 0, stream>>>(attn, wpT, 2048, 2048, 2048, 512,
                                               nullptr, nullptr, projPA, projPB);
  reduce_kernel<4, 0><<<4096, b256, 0, stream>>>(projPA, projPB, bp, x, nullptr, x1,
                                                 4194304, 2048);
  ln_kernel<<<2048, b256, 0, stream>>>(x1, ln2g, ln2b, g);
  // FF1: gelu(g @ W1 + b1) -> bf16
  gemm3<2><<<dim3(32, 8, 1), b512, 0, stream>>>(g, w1T, 2048, 8192, 2048, 2048,
                                                ff1, b1, nullptr, nullptr);
  // FF2: split-K=4 (Kc=2048): partials then fused reduce (+b2 +x1 +g)
  gemm3<4><<<dim3(8, 8, 4), b512, 0, stream>>>(ff1, w2T, 2048, 2048, 8192, 2048,
                                               nullptr, nullptr, ffPA, ffPB);
  reduce_kernel<4, 1><<<4096, b256, 0, stream>>>(ffPA, ffPB, b2, x1, g, out,
                                                 4194304, 2048);
}